// Round 6
// baseline (414.455 us; speedup 1.0000x reference)
//
#include <hip/hip_runtime.h>
#include <hip/hip_bf16.h>
#include <math.h>

#define NEG_SLOPE 0.2f
#define BN_EPS 1e-5f

typedef __attribute__((ext_vector_type(8))) short bf16x8;
typedef __attribute__((ext_vector_type(4))) float f32x4;

__device__ __forceinline__ void atomAddF(float* p, float v) { unsafeAtomicAdd(p, v); }

__device__ __forceinline__ float bf_lo(unsigned u) { return __uint_as_float(u << 16); }
__device__ __forceinline__ float bf_hi(unsigned u) { return __uint_as_float(u & 0xffff0000u); }

// ---------------- prep: cast x -> bf16, transpose W1/W2 -> bf16 ----------------
// grid covers N*128/4 (x cast, float4) + 128*256 (W1) + 256*128 (W2)
__global__ __launch_bounds__(256) void prep_kernel(const float* __restrict__ x,
                                                   const float* __restrict__ W1,
                                                   const float* __restrict__ W2,
                                                   __hip_bfloat16* __restrict__ xbf,
                                                   __hip_bfloat16* __restrict__ WT1,
                                                   __hip_bfloat16* __restrict__ WT2,
                                                   int n4) {
    int i = blockIdx.x * blockDim.x + threadIdx.x;
    if (i < n4) {
        float4 v = ((const float4*)x)[i];
        xbf[i * 4 + 0] = __float2bfloat16(v.x);
        xbf[i * 4 + 1] = __float2bfloat16(v.y);
        xbf[i * 4 + 2] = __float2bfloat16(v.z);
        xbf[i * 4 + 3] = __float2bfloat16(v.w);
        return;
    }
    int j = i - n4;
    if (j < 128 * 256) {          // W1 [128,256] -> WT1 [256,128]
        int k = j >> 8, n = j & 255;
        WT1[(size_t)n * 128 + k] = __float2bfloat16(W1[j]);
        return;
    }
    j -= 128 * 256;
    if (j < 256 * 128) {          // W2 [256,128] -> WT2 [128,256]
        int k = j >> 7, n = j & 127;
        WT2[(size_t)n * 256 + k] = __float2bfloat16(W2[j]);
    }
}

// ---------------- MFMA GEMM: C[M,N] = A[M,K] @ BT[N,K]^T, bf16 in/out -----------
__global__ __launch_bounds__(256) void gemm_bf16_kernel(const __hip_bfloat16* __restrict__ A,
                                                        const __hip_bfloat16* __restrict__ BT,
                                                        __hip_bfloat16* __restrict__ C,
                                                        int M, int N, int K) {
    const int w = threadIdx.x >> 6;
    const int lane = threadIdx.x & 63;
    const int q = lane >> 4;          // 0..3
    const int r16 = lane & 15;
    const int bm = blockIdx.y * 64;
    const int bn = blockIdx.x * 64;
    const int am = bm + w * 16 + r16;
    const int ama = am < M ? am : M - 1;
    f32x4 acc[4] = {};
    for (int k0 = 0; k0 < K; k0 += 32) {
        bf16x8 a = *(const bf16x8*)(A + (size_t)ama * K + k0 + q * 8);
#pragma unroll
        for (int t = 0; t < 4; ++t) {
            bf16x8 b = *(const bf16x8*)(BT + (size_t)(bn + t * 16 + r16) * K + k0 + q * 8);
            acc[t] = __builtin_amdgcn_mfma_f32_16x16x32_bf16(a, b, acc[t], 0, 0, 0);
        }
    }
#pragma unroll
    for (int t = 0; t < 4; ++t)
#pragma unroll
        for (int r = 0; r < 4; ++r) {
            int row = bm + w * 16 + q * 4 + r;
            if (row < M)
                C[(size_t)row * N + bn + t * 16 + r16] = __float2bfloat16(acc[t][r]);
        }
}

// ---------------- CSR build ----------------
__global__ __launch_bounds__(256) void deg_kernel(const int* __restrict__ dst,
                                                  int* __restrict__ deg, int E, int Etot) {
    int e = blockIdx.x * blockDim.x + threadIdx.x;
    if (e >= Etot) return;
    int d = (e < E) ? dst[e] : e - E;
    atomicAdd(deg + d, 1);
}

__global__ __launch_bounds__(1024) void scan_kernel(const int* __restrict__ deg,
                                                    int* __restrict__ rowptr,
                                                    int* __restrict__ cursor, int N) {
    __shared__ int wsum[16];
    const int t = threadIdx.x;
    const int chunk = (N + 1023) / 1024;
    const int s0 = min(t * chunk, N), s1 = min(s0 + chunk, N);
    int sum = 0;
    for (int i = s0; i < s1; ++i) sum += deg[i];
    const int lane = t & 63, w = t >> 6;
    int v = sum;
#pragma unroll
    for (int o = 1; o < 64; o <<= 1) {
        int u = __shfl_up(v, o);
        if (lane >= o) v += u;
    }
    if (lane == 63) wsum[w] = v;
    __syncthreads();
    if (t < 16) {
        int xv = wsum[t];
#pragma unroll
        for (int o = 1; o < 16; o <<= 1) {
            int u = __shfl_up(xv, o);
            if (t >= o) xv += u;
        }
        wsum[t] = xv;
    }
    __syncthreads();
    int excl = v - sum + (w ? wsum[w - 1] : 0);
    int acc = excl;
    for (int i = s0; i < s1; ++i) { rowptr[i] = acc; cursor[i] = acc; acc += deg[i]; }
    if (s1 == N && s0 < N) rowptr[N] = acc;
}

__global__ __launch_bounds__(256) void scatter_kernel(const int* __restrict__ src,
                                                      const int* __restrict__ dst,
                                                      int* __restrict__ cursor,
                                                      int* __restrict__ csr_src,
                                                      int E, int Etot) {
    int e = blockIdx.x * blockDim.x + threadIdx.x;
    if (e >= Etot) return;
    int s, d;
    if (e < E) { s = src[e]; d = dst[e]; } else { s = d = e - E; }
    int pos = atomicAdd(cursor + d, 1);
    csr_src[pos] = s;
}

// ---------------- Layer 1 scores ----------------
__global__ __launch_bounds__(256) void score1_kernel(const __hip_bfloat16* __restrict__ h1,
                                                     const float* __restrict__ asrc,
                                                     const float* __restrict__ adst,
                                                     float* __restrict__ ssrc,
                                                     float* __restrict__ sdst) {
    const int n = blockIdx.x;
    const int tid = threadIdx.x;       // == h*64 + c
    float v = __bfloat162float(h1[(size_t)n * 256 + tid]);
    float ps = v * asrc[tid];
    float pd = v * adst[tid];
#pragma unroll
    for (int o = 32; o; o >>= 1) { ps += __shfl_down(ps, o); pd += __shfl_down(pd, o); }
    const int lane = tid & 63, w = tid >> 6;
    if (lane == 0) { ssrc[n * 4 + w] = ps; sdst[n * 4 + w] = pd; }
}

// ---------------- Layer 1 fused: softmax + aggregate + bias + BN + ELU ----------
// block = dst node, 4 waves = 4 heads. Agg: lane = eo*16+c16, 4ch/lane dwordx2,
// 4 edge slots/wave, x2 unroll (8 gathers in flight), butterfly combine.
__global__ __launch_bounds__(256) void fused1_kernel(const int* __restrict__ csr_src,
                                                     const int* __restrict__ rowptr,
                                                     const float* __restrict__ ssrc,
                                                     const float* __restrict__ sdst,
                                                     const __hip_bfloat16* __restrict__ h1,
                                                     float* __restrict__ ex,
                                                     const float* __restrict__ b,
                                                     const float* __restrict__ g,
                                                     const float* __restrict__ be,
                                                     const float* __restrict__ rm,
                                                     const float* __restrict__ rv,
                                                     __hip_bfloat16* __restrict__ out1,
                                                     int Etot) {
    const int n = blockIdx.x;
    const int tid = threadIdx.x;
    const int h = tid >> 6, lane = tid & 63;
    const int row0 = rowptr[n], row1 = rowptr[n + 1];
    const float sd = sdst[n * 4 + h];
    float* exh = ex + (size_t)h * Etot;

    float m = -1e30f;
    for (int i = row0 + lane; i < row1; i += 64) {
        int s = csr_src[i];
        float sc = ssrc[s * 4 + h] + sd;
        sc = sc > 0.f ? sc : NEG_SLOPE * sc;
        m = fmaxf(m, sc);
    }
#pragma unroll
    for (int o = 32; o; o >>= 1) m = fmaxf(m, __shfl_xor(m, o));

    float den = 0.f;
    for (int i = row0 + lane; i < row1; i += 64) {
        int s = csr_src[i];
        float sc = ssrc[s * 4 + h] + sd;
        sc = sc > 0.f ? sc : NEG_SLOPE * sc;
        float e = __expf(sc - m);
        exh[i] = e;
        den += e;
    }
#pragma unroll
    for (int o = 32; o; o >>= 1) den += __shfl_xor(den, o);
    const float rden = 1.f / (den + 1e-16f);

    // aggregation: 4ch per lane, 4 edge slots per wave, 2x unroll
    const int eo = lane >> 4;          // edge slot 0..3
    const int c16 = lane & 15;
    const int ch = h * 64 + c16 * 4;   // first of 4 channels
    const __hip_bfloat16* hbase = h1 + ch;
    f32x4 acc = {0.f, 0.f, 0.f, 0.f};
    int i = row0 + eo;
    for (; i + 4 < row1; i += 8) {
        int s0 = csr_src[i], s1 = csr_src[i + 4];
        float a0 = exh[i], a1 = exh[i + 4];
        uint2 u0 = *(const uint2*)(hbase + (size_t)s0 * 256);
        uint2 u1 = *(const uint2*)(hbase + (size_t)s1 * 256);
        acc.x += a0 * bf_lo(u0.x); acc.y += a0 * bf_hi(u0.x);
        acc.z += a0 * bf_lo(u0.y); acc.w += a0 * bf_hi(u0.y);
        acc.x += a1 * bf_lo(u1.x); acc.y += a1 * bf_hi(u1.x);
        acc.z += a1 * bf_lo(u1.y); acc.w += a1 * bf_hi(u1.y);
    }
    if (i < row1) {
        int s0 = csr_src[i];
        float a0 = exh[i];
        uint2 u0 = *(const uint2*)(hbase + (size_t)s0 * 256);
        acc.x += a0 * bf_lo(u0.x); acc.y += a0 * bf_hi(u0.x);
        acc.z += a0 * bf_lo(u0.y); acc.w += a0 * bf_hi(u0.y);
    }
#pragma unroll
    for (int mask = 16; mask <= 32; mask <<= 1) {
        acc.x += __shfl_xor(acc.x, mask);
        acc.y += __shfl_xor(acc.y, mask);
        acc.z += __shfl_xor(acc.z, mask);
        acc.w += __shfl_xor(acc.w, mask);
    }
    if (eo == 0) {
        float4 bb = *(const float4*)(b + ch), gg = *(const float4*)(g + ch);
        float4 ee = *(const float4*)(be + ch), mm = *(const float4*)(rm + ch);
        float4 vv = *(const float4*)(rv + ch);
        float o0 = (acc.x * rden + bb.x - mm.x) * rsqrtf(vv.x + BN_EPS) * gg.x + ee.x;
        float o1 = (acc.y * rden + bb.y - mm.y) * rsqrtf(vv.y + BN_EPS) * gg.y + ee.y;
        float o2 = (acc.z * rden + bb.z - mm.z) * rsqrtf(vv.z + BN_EPS) * gg.z + ee.z;
        float o3 = (acc.w * rden + bb.w - mm.w) * rsqrtf(vv.w + BN_EPS) * gg.w + ee.w;
        o0 = o0 > 0.f ? o0 : expm1f(o0);
        o1 = o1 > 0.f ? o1 : expm1f(o1);
        o2 = o2 > 0.f ? o2 : expm1f(o2);
        o3 = o3 > 0.f ? o3 : expm1f(o3);
        ushort4 st;
        st.x = __bfloat16_as_ushort(__float2bfloat16(o0));
        st.y = __bfloat16_as_ushort(__float2bfloat16(o1));
        st.z = __bfloat16_as_ushort(__float2bfloat16(o2));
        st.w = __bfloat16_as_ushort(__float2bfloat16(o3));
        *(ushort4*)(out1 + (size_t)n * 256 + ch) = st;
    }
}

// ---------------- Layer 2 scores (1 head, 128 ch): 4 nodes/block ----------------
__global__ __launch_bounds__(256) void score2_kernel(const __hip_bfloat16* __restrict__ h2,
                                                     const float* __restrict__ asrc,
                                                     const float* __restrict__ adst,
                                                     float* __restrict__ ssrc,
                                                     float* __restrict__ sdst) {
    const int n = blockIdx.x * 4 + (threadIdx.x >> 6);
    const int lane = threadIdx.x & 63;
    float v0 = __bfloat162float(h2[(size_t)n * 128 + lane]);
    float v1 = __bfloat162float(h2[(size_t)n * 128 + 64 + lane]);
    float ps = v0 * asrc[lane] + v1 * asrc[64 + lane];
    float pd = v0 * adst[lane] + v1 * adst[64 + lane];
#pragma unroll
    for (int o = 32; o; o >>= 1) { ps += __shfl_down(ps, o); pd += __shfl_down(pd, o); }
    if (lane == 0) { ssrc[n] = ps; sdst[n] = pd; }
}

// ---------------- Layer 2 fused: 1 wave per node, 4ch/lane, 2 edge slots ----------
__global__ __launch_bounds__(64) void fused2_kernel(const int* __restrict__ csr_src,
                                                    const int* __restrict__ rowptr,
                                                    const float* __restrict__ ssrc,
                                                    const float* __restrict__ sdst,
                                                    const __hip_bfloat16* __restrict__ h2,
                                                    float* __restrict__ ex,
                                                    const float* __restrict__ b,
                                                    const float* __restrict__ g,
                                                    const float* __restrict__ be,
                                                    const float* __restrict__ rm,
                                                    const float* __restrict__ rv,
                                                    float* __restrict__ out2) {
    const int n = blockIdx.x;
    const int lane = threadIdx.x;
    const int row0 = rowptr[n], row1 = rowptr[n + 1];
    const float sd = sdst[n];

    float m = -1e30f;
    for (int i = row0 + lane; i < row1; i += 64) {
        int s = csr_src[i];
        float sc = ssrc[s] + sd;
        sc = sc > 0.f ? sc : NEG_SLOPE * sc;
        m = fmaxf(m, sc);
    }
#pragma unroll
    for (int o = 32; o; o >>= 1) m = fmaxf(m, __shfl_xor(m, o));

    float den = 0.f;
    for (int i = row0 + lane; i < row1; i += 64) {
        int s = csr_src[i];
        float sc = ssrc[s] + sd;
        sc = sc > 0.f ? sc : NEG_SLOPE * sc;
        float e = __expf(sc - m);
        ex[i] = e;
        den += e;
    }
#pragma unroll
    for (int o = 32; o; o >>= 1) den += __shfl_xor(den, o);
    const float rden = 1.f / (den + 1e-16f);

    // agg: 4ch/lane (32 groups), 2 edge slots, 2x unroll (4 gathers in flight)
    const int eo = lane >> 5;          // 0..1
    const int ch = (lane & 31) * 4;
    const __hip_bfloat16* hbase = h2 + ch;
    f32x4 acc = {0.f, 0.f, 0.f, 0.f};
    int i = row0 + eo;
    for (; i + 2 < row1; i += 4) {
        int s0 = csr_src[i], s1 = csr_src[i + 2];
        float a0 = ex[i], a1 = ex[i + 2];
        uint2 u0 = *(const uint2*)(hbase + (size_t)s0 * 128);
        uint2 u1 = *(const uint2*)(hbase + (size_t)s1 * 128);
        acc.x += a0 * bf_lo(u0.x); acc.y += a0 * bf_hi(u0.x);
        acc.z += a0 * bf_lo(u0.y); acc.w += a0 * bf_hi(u0.y);
        acc.x += a1 * bf_lo(u1.x); acc.y += a1 * bf_hi(u1.x);
        acc.z += a1 * bf_lo(u1.y); acc.w += a1 * bf_hi(u1.y);
    }
    if (i < row1) {
        int s0 = csr_src[i];
        float a0 = ex[i];
        uint2 u0 = *(const uint2*)(hbase + (size_t)s0 * 128);
        acc.x += a0 * bf_lo(u0.x); acc.y += a0 * bf_hi(u0.x);
        acc.z += a0 * bf_lo(u0.y); acc.w += a0 * bf_hi(u0.y);
    }
    acc.x += __shfl_xor(acc.x, 32);
    acc.y += __shfl_xor(acc.y, 32);
    acc.z += __shfl_xor(acc.z, 32);
    acc.w += __shfl_xor(acc.w, 32);
    if (eo == 0) {
        float4 bb = *(const float4*)(b + ch), gg = *(const float4*)(g + ch);
        float4 ee = *(const float4*)(be + ch), mm = *(const float4*)(rm + ch);
        float4 vv = *(const float4*)(rv + ch);
        float4 o;
        o.x = (acc.x * rden + bb.x - mm.x) * rsqrtf(vv.x + BN_EPS) * gg.x + ee.x;
        o.y = (acc.y * rden + bb.y - mm.y) * rsqrtf(vv.y + BN_EPS) * gg.y + ee.y;
        o.z = (acc.z * rden + bb.z - mm.z) * rsqrtf(vv.z + BN_EPS) * gg.z + ee.z;
        o.w = (acc.w * rden + bb.w - mm.w) * rsqrtf(vv.w + BN_EPS) * gg.w + ee.w;
        *(float4*)(out2 + (size_t)n * 128 + ch) = o;
    }
}

// ---------------- pooling ----------------
__global__ __launch_bounds__(128) void pool_kernel(const float* __restrict__ out2,
                                                   const int* __restrict__ batch,
                                                   float* __restrict__ pool,
                                                   int N, int npb) {
    const int j = threadIdx.x;
    int n0 = blockIdx.x * npb;
    int n1 = min(n0 + npb, N);
    if (n0 >= n1) return;
    int curg = batch[n0];
    float acc = 0.f;
    for (int n = n0; n < n1; ++n) {
        int gr = batch[n];
        if (gr != curg) {
            atomAddF(pool + (size_t)curg * 128 + j, acc);
            acc = 0.f; curg = gr;
        }
        acc += out2[(size_t)n * 128 + j];
    }
    atomAddF(pool + (size_t)curg * 128 + j, acc);
}

__device__ __forceinline__ int lowerBound(const int* __restrict__ a, int n, int v) {
    int lo = 0, hi = n;
    while (lo < hi) {
        int mid = (lo + hi) >> 1;
        if (a[mid] < v) lo = mid + 1; else hi = mid;
    }
    return lo;
}

__global__ __launch_bounds__(256) void final_kernel(const float* __restrict__ pool,
                                                    const int* __restrict__ batch,
                                                    float* __restrict__ out, int N) {
    int i = blockIdx.x * blockDim.x + threadIdx.x;  // 0..2047
    int g = i >> 7;
    int c = lowerBound(batch, N, g + 1) - lowerBound(batch, N, g);
    out[i] = pool[i] / fmaxf((float)c, 1.f);
}

extern "C" void kernel_launch(void* const* d_in, const int* in_sizes, int n_in,
                              void* d_out, int out_size, void* d_ws, size_t ws_size,
                              hipStream_t stream) {
    const float* x    = (const float*)d_in[0];
    const int* ei     = (const int*)d_in[1];
    const int* batch  = (const int*)d_in[2];
    const float* W1   = (const float*)d_in[3];
    const float* as1  = (const float*)d_in[4];
    const float* ad1  = (const float*)d_in[5];
    const float* b1   = (const float*)d_in[6];
    const float* g1   = (const float*)d_in[7];
    const float* be1  = (const float*)d_in[8];
    const float* rm1  = (const float*)d_in[9];
    const float* rv1  = (const float*)d_in[10];
    const float* W2   = (const float*)d_in[11];
    const float* as2  = (const float*)d_in[12];
    const float* ad2  = (const float*)d_in[13];
    const float* b2   = (const float*)d_in[14];
    const float* g2   = (const float*)d_in[15];
    const float* be2  = (const float*)d_in[16];
    const float* rm2  = (const float*)d_in[17];
    const float* rv2  = (const float*)d_in[18];
    float* out = (float*)d_out;

    const int N = in_sizes[0] / 128;   // 20000
    const int E = in_sizes[1] / 2;     // 640000
    const int Etot = E + N;
    const int* src = ei;
    const int* dst = ei + E;

    // workspace carve (256B-aligned)
    char* p = (char*)d_ws;
    auto alloc = [&](size_t bytes) { char* r = p; p += (bytes + 255) & ~(size_t)255; return r; };
    __hip_bfloat16* h1   = (__hip_bfloat16*)alloc((size_t)N * 256 * 2);
    __hip_bfloat16* out1 = (__hip_bfloat16*)alloc((size_t)N * 256 * 2);
    float* out2          = (float*)alloc((size_t)N * 128 * 4);
    __hip_bfloat16* xbf  = (__hip_bfloat16*)alloc((size_t)N * 128 * 2);
    __hip_bfloat16* WT1  = (__hip_bfloat16*)alloc(256 * 128 * 2);
    __hip_bfloat16* WT2  = (__hip_bfloat16*)alloc(128 * 256 * 2);
    float* ssrc1         = (float*)alloc((size_t)N * 4 * 4);
    float* sdst1         = (float*)alloc((size_t)N * 4 * 4);
    float* ssrc2         = (float*)alloc((size_t)N * 4);
    float* sdst2         = (float*)alloc((size_t)N * 4);
    float* pool          = (float*)alloc(2048 * 4);
    int*   deg           = (int*)alloc((size_t)N * 4);
    int*   rowptr        = (int*)alloc((size_t)(N + 1) * 4);
    int*   cursor        = (int*)alloc((size_t)N * 4);
    int*   csrs          = (int*)alloc((size_t)Etot * 4);
    float* ex            = (float*)alloc((size_t)Etot * 4 * 4);  // [4][Etot] L1; L2 reuses [0]
    __hip_bfloat16* h2   = h1;   // alias (h1 dead after fused1)

    const int eb = (Etot + 255) / 256;

    hipMemsetAsync(deg, 0, (size_t)N * sizeof(int), stream);
    hipMemsetAsync(pool, 0, 2048 * sizeof(float), stream);

    // ---- prep + CSR build ----
    const int n4 = N * 128 / 4;
    prep_kernel<<<(n4 + 2 * 128 * 256 + 255) / 256, 256, 0, stream>>>(x, W1, W2, xbf, WT1, WT2, n4);
    deg_kernel<<<eb, 256, 0, stream>>>(dst, deg, E, Etot);
    scan_kernel<<<1, 1024, 0, stream>>>(deg, rowptr, cursor, N);
    scatter_kernel<<<eb, 256, 0, stream>>>(src, dst, cursor, csrs, E, Etot);

    // ---- layer 1 ----
    gemm_bf16_kernel<<<dim3(256 / 64, (N + 63) / 64), 256, 0, stream>>>(xbf, WT1, h1, N, 256, 128);
    score1_kernel<<<N, 256, 0, stream>>>(h1, as1, ad1, ssrc1, sdst1);
    fused1_kernel<<<N, 256, 0, stream>>>(csrs, rowptr, ssrc1, sdst1, h1, ex,
                                         b1, g1, be1, rm1, rv1, out1, Etot);
    // ---- layer 2 ----
    gemm_bf16_kernel<<<dim3(128 / 64, (N + 63) / 64), 256, 0, stream>>>(out1, WT2, h2, N, 128, 256);
    score2_kernel<<<N / 4, 256, 0, stream>>>(h2, as2, ad2, ssrc2, sdst2);
    fused2_kernel<<<N, 64, 0, stream>>>(csrs, rowptr, ssrc2, sdst2, h2, ex,
                                        b2, g2, be2, rm2, rv2, out2);

    // ---- pool ----
    pool_kernel<<<(N + 159) / 160, 128, 0, stream>>>(out2, batch, pool, N, 160);
    final_kernel<<<8, 256, 0, stream>>>(pool, batch, out, N);
}

// Round 8
// 348.625 us; speedup vs baseline: 1.1888x; 1.1888x over previous
//
#include <hip/hip_runtime.h>
#include <hip/hip_bf16.h>
#include <math.h>

#define NEG_SLOPE 0.2f
#define BN_EPS 1e-5f
#define CAP 256          // per-node LDS edge cap (deg ~ Poisson(33); overflow path below)

typedef __attribute__((ext_vector_type(8))) short bf16x8;
typedef __attribute__((ext_vector_type(4))) float f32x4;

__device__ __forceinline__ void atomAddF(float* p, float v) { unsafeAtomicAdd(p, v); }
__device__ __forceinline__ float bf_lo(unsigned u) { return __uint_as_float(u << 16); }
__device__ __forceinline__ float bf_hi(unsigned u) { return __uint_as_float(u & 0xffff0000u); }
__device__ __forceinline__ float lk(float x) { return x > 0.f ? x : NEG_SLOPE * x; }

// ---------------- prep: cast x -> bf16, transpose W1/W2 -> bf16 ----------------
__global__ __launch_bounds__(256) void prep_kernel(const float* __restrict__ x,
                                                   const float* __restrict__ W1,
                                                   const float* __restrict__ W2,
                                                   __hip_bfloat16* __restrict__ xbf,
                                                   __hip_bfloat16* __restrict__ WT1,
                                                   __hip_bfloat16* __restrict__ WT2,
                                                   int n4) {
    int i = blockIdx.x * blockDim.x + threadIdx.x;
    if (i < n4) {
        float4 v = ((const float4*)x)[i];
        xbf[i * 4 + 0] = __float2bfloat16(v.x);
        xbf[i * 4 + 1] = __float2bfloat16(v.y);
        xbf[i * 4 + 2] = __float2bfloat16(v.z);
        xbf[i * 4 + 3] = __float2bfloat16(v.w);
        return;
    }
    int j = i - n4;
    if (j < 128 * 256) {          // W1 [128,256] -> WT1 [256,128]
        int k = j >> 8, n = j & 255;
        WT1[(size_t)n * 128 + k] = __float2bfloat16(W1[j]);
        return;
    }
    j -= 128 * 256;
    if (j < 256 * 128) {          // W2 [256,128] -> WT2 [128,256]
        int k = j >> 7, n = j & 127;
        WT2[(size_t)n * 256 + k] = __float2bfloat16(W2[j]);
    }
}

// ---------------- MFMA GEMM: C[M,N] = A[M,K] @ BT[N,K]^T, bf16 in/out -----------
__global__ __launch_bounds__(256) void gemm_bf16_kernel(const __hip_bfloat16* __restrict__ A,
                                                        const __hip_bfloat16* __restrict__ BT,
                                                        __hip_bfloat16* __restrict__ C,
                                                        int M, int N, int K) {
    const int w = threadIdx.x >> 6;
    const int lane = threadIdx.x & 63;
    const int q = lane >> 4;
    const int r16 = lane & 15;
    const int bm = blockIdx.y * 64;
    const int bn = blockIdx.x * 64;
    const int am = bm + w * 16 + r16;
    const int ama = am < M ? am : M - 1;
    f32x4 acc[4] = {};
    for (int k0 = 0; k0 < K; k0 += 32) {
        bf16x8 a = *(const bf16x8*)(A + (size_t)ama * K + k0 + q * 8);
#pragma unroll
        for (int t = 0; t < 4; ++t) {
            bf16x8 b = *(const bf16x8*)(BT + (size_t)(bn + t * 16 + r16) * K + k0 + q * 8);
            acc[t] = __builtin_amdgcn_mfma_f32_16x16x32_bf16(a, b, acc[t], 0, 0, 0);
        }
    }
#pragma unroll
    for (int t = 0; t < 4; ++t)
#pragma unroll
        for (int r = 0; r < 4; ++r) {
            int row = bm + w * 16 + q * 4 + r;
            if (row < M)
                C[(size_t)row * N + bn + t * 16 + r16] = __float2bfloat16(acc[t][r]);
        }
}

// ---------------- CSR build ----------------
__global__ __launch_bounds__(256) void deg_kernel(const int* __restrict__ dst,
                                                  int* __restrict__ deg, int E, int Etot) {
    int e = blockIdx.x * blockDim.x + threadIdx.x;
    if (e >= Etot) return;
    int d = (e < E) ? dst[e] : e - E;
    atomicAdd(deg + d, 1);
}

__global__ __launch_bounds__(1024) void scan_kernel(const int* __restrict__ deg,
                                                    int* __restrict__ rowptr,
                                                    int* __restrict__ cursor, int N) {
    __shared__ int wsum[16];
    const int t = threadIdx.x;
    const int chunk = (N + 1023) / 1024;
    const int s0 = min(t * chunk, N), s1 = min(s0 + chunk, N);
    int sum = 0;
    for (int i = s0; i < s1; ++i) sum += deg[i];
    const int lane = t & 63, w = t >> 6;
    int v = sum;
#pragma unroll
    for (int o = 1; o < 64; o <<= 1) {
        int u = __shfl_up(v, o);
        if (lane >= o) v += u;
    }
    if (lane == 63) wsum[w] = v;
    __syncthreads();
    if (t < 16) {
        int xv = wsum[t];
#pragma unroll
        for (int o = 1; o < 16; o <<= 1) {
            int u = __shfl_up(xv, o);
            if (t >= o) xv += u;
        }
        wsum[t] = xv;
    }
    __syncthreads();
    int excl = v - sum + (w ? wsum[w - 1] : 0);
    int acc = excl;
    for (int i = s0; i < s1; ++i) { rowptr[i] = acc; cursor[i] = acc; acc += deg[i]; }
    if (s1 == N && s0 < N) rowptr[N] = acc;
}

__global__ __launch_bounds__(256) void scatter_kernel(const int* __restrict__ src,
                                                      const int* __restrict__ dst,
                                                      int* __restrict__ cursor,
                                                      int* __restrict__ csr_src,
                                                      int E, int Etot) {
    int e = blockIdx.x * blockDim.x + threadIdx.x;
    if (e >= Etot) return;
    int s, d;
    if (e < E) { s = src[e]; d = dst[e]; } else { s = d = e - E; }
    int pos = atomicAdd(cursor + d, 1);
    csr_src[pos] = s;
}

// ---------------- Layer 1 scores ----------------
__global__ __launch_bounds__(256) void score1_kernel(const __hip_bfloat16* __restrict__ h1,
                                                     const float* __restrict__ asrc,
                                                     const float* __restrict__ adst,
                                                     float* __restrict__ ssrc,
                                                     float* __restrict__ sdst) {
    const int n = blockIdx.x;
    const int tid = threadIdx.x;       // == h*64 + c
    float v = __bfloat162float(h1[(size_t)n * 256 + tid]);
    float ps = v * asrc[tid];
    float pd = v * adst[tid];
#pragma unroll
    for (int o = 32; o; o >>= 1) { ps += __shfl_down(ps, o); pd += __shfl_down(pd, o); }
    const int lane = tid & 63, w = tid >> 6;
    if (lane == 0) { ssrc[n * 4 + w] = ps; sdst[n * 4 + w] = pd; }
}

// ---------------- Layer 1 fused: wave = dst node, whole-row gathers -------------
// lane = h*16 + c16 covers channels ch..ch+3 (ch = h*64 + c16*4); one uint2 load
// per edge per wave fetches the full 512B h1 row. csr_src[i] stays wave-uniform.
__global__ __launch_bounds__(256) void fused1_kernel(const int* __restrict__ csr_src,
                                                     const int* __restrict__ rowptr,
                                                     const float* __restrict__ ssrc,
                                                     const float* __restrict__ sdst,
                                                     const __hip_bfloat16* __restrict__ h1,
                                                     const float* __restrict__ b,
                                                     const float* __restrict__ g,
                                                     const float* __restrict__ be,
                                                     const float* __restrict__ rm,
                                                     const float* __restrict__ rv,
                                                     __hip_bfloat16* __restrict__ out1,
                                                     int N) {
    __shared__ float4 sex[4][CAP];
    const int w = threadIdx.x >> 6;
    const int lane = threadIdx.x & 63;
    const int n = blockIdx.x * 4 + w;
    if (n >= N) return;
    const int row0 = rowptr[n], row1 = rowptr[n + 1];
    const float4 sd4 = *(const float4*)(sdst + (size_t)n * 4);

    // pass 1: leaky scores -> LDS, running max (per head)
    float4 m4 = {-1e30f, -1e30f, -1e30f, -1e30f};
    for (int i = row0 + lane; i < row1; i += 64) {
        int s = csr_src[i];
        float4 sc = *(const float4*)(ssrc + (size_t)s * 4);
        sc.x = lk(sc.x + sd4.x); sc.y = lk(sc.y + sd4.y);
        sc.z = lk(sc.z + sd4.z); sc.w = lk(sc.w + sd4.w);
        int idx = i - row0;
        if (idx < CAP) sex[w][idx] = sc;
        m4.x = fmaxf(m4.x, sc.x); m4.y = fmaxf(m4.y, sc.y);
        m4.z = fmaxf(m4.z, sc.z); m4.w = fmaxf(m4.w, sc.w);
    }
#pragma unroll
    for (int o = 32; o; o >>= 1) {
        m4.x = fmaxf(m4.x, __shfl_xor(m4.x, o));
        m4.y = fmaxf(m4.y, __shfl_xor(m4.y, o));
        m4.z = fmaxf(m4.z, __shfl_xor(m4.z, o));
        m4.w = fmaxf(m4.w, __shfl_xor(m4.w, o));
    }

    // pass 2: exp in place, denominator
    float4 d4 = {0.f, 0.f, 0.f, 0.f};
    for (int i = row0 + lane; i < row1; i += 64) {
        int idx = i - row0;
        float4 sc;
        if (idx < CAP) sc = sex[w][idx];
        else {
            int s = csr_src[i];
            sc = *(const float4*)(ssrc + (size_t)s * 4);
            sc.x = lk(sc.x + sd4.x); sc.y = lk(sc.y + sd4.y);
            sc.z = lk(sc.z + sd4.z); sc.w = lk(sc.w + sd4.w);
        }
        float4 e4;
        e4.x = __expf(sc.x - m4.x); e4.y = __expf(sc.y - m4.y);
        e4.z = __expf(sc.z - m4.z); e4.w = __expf(sc.w - m4.w);
        if (idx < CAP) sex[w][idx] = e4;
        d4.x += e4.x; d4.y += e4.y; d4.z += e4.z; d4.w += e4.w;
    }
#pragma unroll
    for (int o = 32; o; o >>= 1) {
        d4.x += __shfl_xor(d4.x, o); d4.y += __shfl_xor(d4.y, o);
        d4.z += __shfl_xor(d4.z, o); d4.w += __shfl_xor(d4.w, o);
    }

    // pass 3: aggregate; lane covers 4 channels of head h
    const int h = lane >> 4, c16 = lane & 15;
    const int ch = h * 64 + c16 * 4;
    const float denh = h == 0 ? d4.x : h == 1 ? d4.y : h == 2 ? d4.z : d4.w;
    const float rden = 1.f / (denh + 1e-16f);
    const __hip_bfloat16* hbase = h1 + ch;
    const float* exw = (const float*)&sex[w][0];

    f32x4 acc = {0.f, 0.f, 0.f, 0.f};
    const int end1 = min(row1, row0 + CAP);
    int i = row0;
    for (; i + 3 < end1; i += 4) {
        int s0 = csr_src[i], s1 = csr_src[i + 1], s2 = csr_src[i + 2], s3 = csr_src[i + 3];
        float a0 = exw[(i - row0) * 4 + h];
        float a1 = exw[(i - row0 + 1) * 4 + h];
        float a2 = exw[(i - row0 + 2) * 4 + h];
        float a3 = exw[(i - row0 + 3) * 4 + h];
        uint2 u0 = *(const uint2*)(hbase + (size_t)s0 * 256);
        uint2 u1 = *(const uint2*)(hbase + (size_t)s1 * 256);
        uint2 u2 = *(const uint2*)(hbase + (size_t)s2 * 256);
        uint2 u3 = *(const uint2*)(hbase + (size_t)s3 * 256);
        acc.x += a0 * bf_lo(u0.x); acc.y += a0 * bf_hi(u0.x);
        acc.z += a0 * bf_lo(u0.y); acc.w += a0 * bf_hi(u0.y);
        acc.x += a1 * bf_lo(u1.x); acc.y += a1 * bf_hi(u1.x);
        acc.z += a1 * bf_lo(u1.y); acc.w += a1 * bf_hi(u1.y);
        acc.x += a2 * bf_lo(u2.x); acc.y += a2 * bf_hi(u2.x);
        acc.z += a2 * bf_lo(u2.y); acc.w += a2 * bf_hi(u2.y);
        acc.x += a3 * bf_lo(u3.x); acc.y += a3 * bf_hi(u3.x);
        acc.z += a3 * bf_lo(u3.y); acc.w += a3 * bf_hi(u3.y);
    }
    for (; i < end1; ++i) {
        int s0 = csr_src[i];
        float a0 = exw[(i - row0) * 4 + h];
        uint2 u0 = *(const uint2*)(hbase + (size_t)s0 * 256);
        acc.x += a0 * bf_lo(u0.x); acc.y += a0 * bf_hi(u0.x);
        acc.z += a0 * bf_lo(u0.y); acc.w += a0 * bf_hi(u0.y);
    }
    // overflow path (deg > CAP): recompute alpha inline — cold, correctness only
    if (i < row1) {
        const float mh = h == 0 ? m4.x : h == 1 ? m4.y : h == 2 ? m4.z : m4.w;
        const float sdh = h == 0 ? sd4.x : h == 1 ? sd4.y : h == 2 ? sd4.z : sd4.w;
        for (; i < row1; ++i) {
            int s0 = csr_src[i];
            float a0 = __expf(lk(ssrc[(size_t)s0 * 4 + h] + sdh) - mh);
            uint2 u0 = *(const uint2*)(hbase + (size_t)s0 * 256);
            acc.x += a0 * bf_lo(u0.x); acc.y += a0 * bf_hi(u0.x);
            acc.z += a0 * bf_lo(u0.y); acc.w += a0 * bf_hi(u0.y);
        }
    }
    // epilogue: rden + bias + BN + ELU, 8B store
    float4 bb = *(const float4*)(b + ch), gg = *(const float4*)(g + ch);
    float4 ee = *(const float4*)(be + ch), mm = *(const float4*)(rm + ch);
    float4 vv = *(const float4*)(rv + ch);
    float o0 = (acc.x * rden + bb.x - mm.x) * rsqrtf(vv.x + BN_EPS) * gg.x + ee.x;
    float o1 = (acc.y * rden + bb.y - mm.y) * rsqrtf(vv.y + BN_EPS) * gg.y + ee.y;
    float o2 = (acc.z * rden + bb.z - mm.z) * rsqrtf(vv.z + BN_EPS) * gg.z + ee.z;
    float o3 = (acc.w * rden + bb.w - mm.w) * rsqrtf(vv.w + BN_EPS) * gg.w + ee.w;
    o0 = o0 > 0.f ? o0 : expm1f(o0);
    o1 = o1 > 0.f ? o1 : expm1f(o1);
    o2 = o2 > 0.f ? o2 : expm1f(o2);
    o3 = o3 > 0.f ? o3 : expm1f(o3);
    ushort4 st;
    st.x = __bfloat16_as_ushort(__float2bfloat16(o0));
    st.y = __bfloat16_as_ushort(__float2bfloat16(o1));
    st.z = __bfloat16_as_ushort(__float2bfloat16(o2));
    st.w = __bfloat16_as_ushort(__float2bfloat16(o3));
    *(ushort4*)(out1 + (size_t)n * 256 + ch) = st;
}

// ---------------- Layer 2 scores (1 head, 128 ch): 4 nodes/block ----------------
__global__ __launch_bounds__(256) void score2_kernel(const __hip_bfloat16* __restrict__ h2,
                                                     const float* __restrict__ asrc,
                                                     const float* __restrict__ adst,
                                                     float* __restrict__ ssrc,
                                                     float* __restrict__ sdst) {
    const int n = blockIdx.x * 4 + (threadIdx.x >> 6);
    const int lane = threadIdx.x & 63;
    float v0 = __bfloat162float(h2[(size_t)n * 128 + lane]);
    float v1 = __bfloat162float(h2[(size_t)n * 128 + 64 + lane]);
    float ps = v0 * asrc[lane] + v1 * asrc[64 + lane];
    float pd = v0 * adst[lane] + v1 * adst[64 + lane];
#pragma unroll
    for (int o = 32; o; o >>= 1) { ps += __shfl_down(ps, o); pd += __shfl_down(pd, o); }
    if (lane == 0) { ssrc[n] = ps; sdst[n] = pd; }
}

// ---------------- Layer 2 fused: wave = node, 2ch/lane dword gathers -------------
__global__ __launch_bounds__(256) void fused2_kernel(const int* __restrict__ csr_src,
                                                     const int* __restrict__ rowptr,
                                                     const float* __restrict__ ssrc,
                                                     const float* __restrict__ sdst,
                                                     const __hip_bfloat16* __restrict__ h2,
                                                     const float* __restrict__ b,
                                                     const float* __restrict__ g,
                                                     const float* __restrict__ be,
                                                     const float* __restrict__ rm,
                                                     const float* __restrict__ rv,
                                                     float* __restrict__ out2,
                                                     int N) {
    __shared__ float sex[4][CAP];
    const int w = threadIdx.x >> 6;
    const int lane = threadIdx.x & 63;
    const int n = blockIdx.x * 4 + w;
    if (n >= N) return;
    const int row0 = rowptr[n], row1 = rowptr[n + 1];
    const float sd = sdst[n];

    float m = -1e30f;
    for (int i = row0 + lane; i < row1; i += 64) {
        int s = csr_src[i];
        float sc = lk(ssrc[s] + sd);
        int idx = i - row0;
        if (idx < CAP) sex[w][idx] = sc;
        m = fmaxf(m, sc);
    }
#pragma unroll
    for (int o = 32; o; o >>= 1) m = fmaxf(m, __shfl_xor(m, o));

    float den = 0.f;
    for (int i = row0 + lane; i < row1; i += 64) {
        int idx = i - row0;
        float sc = (idx < CAP) ? sex[w][idx] : lk(ssrc[csr_src[i]] + sd);
        float e = __expf(sc - m);
        if (idx < CAP) sex[w][idx] = e;
        den += e;
    }
#pragma unroll
    for (int o = 32; o; o >>= 1) den += __shfl_xor(den, o);
    const float rden = 1.f / (den + 1e-16f);

    const int ch = lane * 2;
    const __hip_bfloat16* hbase = h2 + ch;
    float ax = 0.f, ay = 0.f;
    const int end1 = min(row1, row0 + CAP);
    int i = row0;
    for (; i + 3 < end1; i += 4) {
        int s0 = csr_src[i], s1 = csr_src[i + 1], s2 = csr_src[i + 2], s3 = csr_src[i + 3];
        float a0 = sex[w][i - row0], a1 = sex[w][i - row0 + 1];
        float a2 = sex[w][i - row0 + 2], a3 = sex[w][i - row0 + 3];
        unsigned u0 = *(const unsigned*)(hbase + (size_t)s0 * 128);
        unsigned u1 = *(const unsigned*)(hbase + (size_t)s1 * 128);
        unsigned u2 = *(const unsigned*)(hbase + (size_t)s2 * 128);
        unsigned u3 = *(const unsigned*)(hbase + (size_t)s3 * 128);
        ax += a0 * bf_lo(u0); ay += a0 * bf_hi(u0);
        ax += a1 * bf_lo(u1); ay += a1 * bf_hi(u1);
        ax += a2 * bf_lo(u2); ay += a2 * bf_hi(u2);
        ax += a3 * bf_lo(u3); ay += a3 * bf_hi(u3);
    }
    for (; i < end1; ++i) {
        int s0 = csr_src[i];
        float a0 = sex[w][i - row0];
        unsigned u0 = *(const unsigned*)(hbase + (size_t)s0 * 128);
        ax += a0 * bf_lo(u0); ay += a0 * bf_hi(u0);
    }
    for (; i < row1; ++i) {   // overflow (cold)
        int s0 = csr_src[i];
        float a0 = __expf(lk(ssrc[s0] + sd) - m);
        unsigned u0 = *(const unsigned*)(hbase + (size_t)s0 * 128);
        ax += a0 * bf_lo(u0); ay += a0 * bf_hi(u0);
    }
    float2 bb = *(const float2*)(b + ch), gg = *(const float2*)(g + ch);
    float2 ee = *(const float2*)(be + ch), mm = *(const float2*)(rm + ch);
    float2 vv = *(const float2*)(rv + ch);
    float2 o;
    o.x = (ax * rden + bb.x - mm.x) * rsqrtf(vv.x + BN_EPS) * gg.x + ee.x;
    o.y = (ay * rden + bb.y - mm.y) * rsqrtf(vv.y + BN_EPS) * gg.y + ee.y;
    *(float2*)(out2 + (size_t)n * 128 + ch) = o;
}

// ---------------- pooling ----------------
__global__ __launch_bounds__(128) void pool_kernel(const float* __restrict__ out2,
                                                   const int* __restrict__ batch,
                                                   float* __restrict__ pool,
                                                   int N, int npb) {
    const int j = threadIdx.x;
    int n0 = blockIdx.x * npb;
    int n1 = min(n0 + npb, N);
    if (n0 >= n1) return;
    int curg = batch[n0];
    float acc = 0.f;
    for (int n = n0; n < n1; ++n) {
        int gr = batch[n];
        if (gr != curg) {
            atomAddF(pool + (size_t)curg * 128 + j, acc);
            acc = 0.f; curg = gr;
        }
        acc += out2[(size_t)n * 128 + j];
    }
    atomAddF(pool + (size_t)curg * 128 + j, acc);
}

__device__ __forceinline__ int lowerBound(const int* __restrict__ a, int n, int v) {
    int lo = 0, hi = n;
    while (lo < hi) {
        int mid = (lo + hi) >> 1;
        if (a[mid] < v) lo = mid + 1; else hi = mid;
    }
    return lo;
}

__global__ __launch_bounds__(256) void final_kernel(const float* __restrict__ pool,
                                                    const int* __restrict__ batch,
                                                    float* __restrict__ out, int N) {
    int i = blockIdx.x * blockDim.x + threadIdx.x;  // 0..2047
    int g = i >> 7;
    int c = lowerBound(batch, N, g + 1) - lowerBound(batch, N, g);
    out[i] = pool[i] / fmaxf((float)c, 1.f);
}

extern "C" void kernel_launch(void* const* d_in, const int* in_sizes, int n_in,
                              void* d_out, int out_size, void* d_ws, size_t ws_size,
                              hipStream_t stream) {
    const float* x    = (const float*)d_in[0];
    const int* ei     = (const int*)d_in[1];
    const int* batch  = (const int*)d_in[2];
    const float* W1   = (const float*)d_in[3];
    const float* as1  = (const float*)d_in[4];
    const float* ad1  = (const float*)d_in[5];
    const float* b1   = (const float*)d_in[6];
    const float* g1   = (const float*)d_in[7];
    const float* be1  = (const float*)d_in[8];
    const float* rm1  = (const float*)d_in[9];
    const float* rv1  = (const float*)d_in[10];
    const float* W2   = (const float*)d_in[11];
    const float* as2  = (const float*)d_in[12];
    const float* ad2  = (const float*)d_in[13];
    const float* b2   = (const float*)d_in[14];
    const float* g2   = (const float*)d_in[15];
    const float* be2  = (const float*)d_in[16];
    const float* rm2  = (const float*)d_in[17];
    const float* rv2  = (const float*)d_in[18];
    float* out = (float*)d_out;

    const int N = in_sizes[0] / 128;   // 20000
    const int E = in_sizes[1] / 2;     // 640000
    const int Etot = E + N;
    const int* src = ei;
    const int* dst = ei + E;

    // workspace carve (256B-aligned)
    char* p = (char*)d_ws;
    auto alloc = [&](size_t bytes) { char* r = p; p += (bytes + 255) & ~(size_t)255; return r; };
    __hip_bfloat16* h1   = (__hip_bfloat16*)alloc((size_t)N * 256 * 2);
    __hip_bfloat16* out1 = (__hip_bfloat16*)alloc((size_t)N * 256 * 2);
    float* out2          = (float*)alloc((size_t)N * 128 * 4);
    __hip_bfloat16* xbf  = (__hip_bfloat16*)alloc((size_t)N * 128 * 2);
    __hip_bfloat16* WT1  = (__hip_bfloat16*)alloc(256 * 128 * 2);
    __hip_bfloat16* WT2  = (__hip_bfloat16*)alloc(128 * 256 * 2);
    float* ssrc1         = (float*)alloc((size_t)N * 4 * 4);
    float* sdst1         = (float*)alloc((size_t)N * 4 * 4);
    float* ssrc2         = (float*)alloc((size_t)N * 4);
    float* sdst2         = (float*)alloc((size_t)N * 4);
    float* pool          = (float*)alloc(2048 * 4);
    int*   deg           = (int*)alloc((size_t)N * 4);
    int*   rowptr        = (int*)alloc((size_t)(N + 1) * 4);
    int*   cursor        = (int*)alloc((size_t)N * 4);
    int*   csrs          = (int*)alloc((size_t)Etot * 4);
    __hip_bfloat16* h2   = h1;   // alias (h1 dead after fused1)

    const int eb = (Etot + 255) / 256;

    hipMemsetAsync(deg, 0, (size_t)N * sizeof(int), stream);
    hipMemsetAsync(pool, 0, 2048 * sizeof(float), stream);

    // ---- prep + CSR build ----
    const int n4 = N * 128 / 4;
    prep_kernel<<<(n4 + 2 * 128 * 256 + 255) / 256, 256, 0, stream>>>(x, W1, W2, xbf, WT1, WT2, n4);
    deg_kernel<<<eb, 256, 0, stream>>>(dst, deg, E, Etot);
    scan_kernel<<<1, 1024, 0, stream>>>(deg, rowptr, cursor, N);
    scatter_kernel<<<eb, 256, 0, stream>>>(src, dst, cursor, csrs, E, Etot);

    // ---- layer 1 ----
    gemm_bf16_kernel<<<dim3(256 / 64, (N + 63) / 64), 256, 0, stream>>>(xbf, WT1, h1, N, 256, 128);
    score1_kernel<<<N, 256, 0, stream>>>(h1, as1, ad1, ssrc1, sdst1);
    fused1_kernel<<<(N + 3) / 4, 256, 0, stream>>>(csrs, rowptr, ssrc1, sdst1, h1,
                                                   b1, g1, be1, rm1, rv1, out1, N);
    // ---- layer 2 ----
    gemm_bf16_kernel<<<dim3(128 / 64, (N + 63) / 64), 256, 0, stream>>>(out1, WT2, h2, N, 128, 256);
    score2_kernel<<<N / 4, 256, 0, stream>>>(h2, as2, ad2, ssrc2, sdst2);
    fused2_kernel<<<(N + 3) / 4, 256, 0, stream>>>(csrs, rowptr, ssrc2, sdst2, h2,
                                                   b2, g2, be2, rm2, rv2, out2, N);

    // ---- pool ----
    pool_kernel<<<(N + 39) / 40, 128, 0, stream>>>(out2, batch, pool, N, 40);
    final_kernel<<<8, 256, 0, stream>>>(pool, batch, out, N);
}

// Round 9
// 322.538 us; speedup vs baseline: 1.2850x; 1.0809x over previous
//
#include <hip/hip_runtime.h>
#include <hip/hip_bf16.h>
#include <math.h>

#define NEG_SLOPE 0.2f
#define BN_EPS 1e-5f
#define CAP 256          // per-node LDS edge cap (deg ~ Poisson(33); overflow path below)

typedef __attribute__((ext_vector_type(8))) short bf16x8;
typedef __attribute__((ext_vector_type(4))) float f32x4;

__device__ __forceinline__ void atomAddF(float* p, float v) { unsafeAtomicAdd(p, v); }
__device__ __forceinline__ float bf_lo(unsigned u) { return __uint_as_float(u << 16); }
__device__ __forceinline__ float bf_hi(unsigned u) { return __uint_as_float(u & 0xffff0000u); }
__device__ __forceinline__ float lk(float x) { return x > 0.f ? x : NEG_SLOPE * x; }

// ------------- prep + deg: cast x, transpose W1/W2, degree histogram ------------
__global__ __launch_bounds__(256) void prep_deg_kernel(const float* __restrict__ x,
                                                       const float* __restrict__ W1,
                                                       const float* __restrict__ W2,
                                                       const int* __restrict__ dst,
                                                       __hip_bfloat16* __restrict__ xbf,
                                                       __hip_bfloat16* __restrict__ WT1,
                                                       __hip_bfloat16* __restrict__ WT2,
                                                       int* __restrict__ deg,
                                                       int n4, int E, int Etot) {
    int i = blockIdx.x * blockDim.x + threadIdx.x;
    if (i < n4) {
        float4 v = ((const float4*)x)[i];
        xbf[i * 4 + 0] = __float2bfloat16(v.x);
        xbf[i * 4 + 1] = __float2bfloat16(v.y);
        xbf[i * 4 + 2] = __float2bfloat16(v.z);
        xbf[i * 4 + 3] = __float2bfloat16(v.w);
        return;
    }
    int j = i - n4;
    if (j < 128 * 256) {          // W1 [128,256] -> WT1 [256,128]
        int k = j >> 8, n = j & 255;
        WT1[(size_t)n * 128 + k] = __float2bfloat16(W1[j]);
        return;
    }
    j -= 128 * 256;
    if (j < 256 * 128) {          // W2 [256,128] -> WT2 [128,256]
        int k = j >> 7, n = j & 127;
        WT2[(size_t)n * 256 + k] = __float2bfloat16(W2[j]);
        return;
    }
    j -= 256 * 128;
    if (j < Etot) {
        int d = (j < E) ? dst[j] : j - E;
        atomicAdd(deg + d, 1);
    }
}

// ------ MFMA GEMM, LDS-staged: C[M,N] = A[M,K] @ BT[N,K]^T, bf16 in/out ---------
// Fused score epilogue: per-row s_src/s_dst partial over this block's 64 cols,
// reduced in-register, atomically added (heads=4: block col == head; heads=1: 2
// col-blocks accumulate). heads==0 disables.
#define LDP 68   // LDS row stride in elements (136B) — kills ds_read_b128 conflicts
__global__ __launch_bounds__(256) void gemm_score_kernel(const __hip_bfloat16* __restrict__ A,
                                                         const __hip_bfloat16* __restrict__ BT,
                                                         __hip_bfloat16* __restrict__ C,
                                                         const float* __restrict__ asrc,
                                                         const float* __restrict__ adst,
                                                         float* __restrict__ ssrc,
                                                         float* __restrict__ sdst,
                                                         int M, int N, int K, int heads) {
    __shared__ __hip_bfloat16 As[64 * LDP];
    __shared__ __hip_bfloat16 Bs[64 * LDP];
    const int tid = threadIdx.x;
    const int w = tid >> 6;
    const int lane = tid & 63;
    const int q = lane >> 4;
    const int r16 = lane & 15;
    const int bm = blockIdx.y * 64;
    const int bn = blockIdx.x * 64;
    const int lrow = tid >> 3;        // 0..31 (two rows per thread: lrow, lrow+32)
    const int lseg = tid & 7;         // 8 x bf16x8 segments per 64-col row
    f32x4 acc[4] = {};

    for (int k0 = 0; k0 < K; k0 += 64) {
#pragma unroll
        for (int half = 0; half < 2; ++half) {
            int row = lrow + half * 32;
            int ga = min(bm + row, M - 1);
            *(bf16x8*)(&As[row * LDP + lseg * 8]) =
                *(const bf16x8*)(A + (size_t)ga * K + k0 + lseg * 8);
            *(bf16x8*)(&Bs[row * LDP + lseg * 8]) =
                *(const bf16x8*)(BT + (size_t)(bn + row) * K + k0 + lseg * 8);
        }
        __syncthreads();
#pragma unroll
        for (int kk = 0; kk < 64; kk += 32) {
            bf16x8 a = *(const bf16x8*)(&As[(w * 16 + r16) * LDP + kk + q * 8]);
#pragma unroll
            for (int t = 0; t < 4; ++t) {
                bf16x8 b = *(const bf16x8*)(&Bs[(t * 16 + r16) * LDP + kk + q * 8]);
                acc[t] = __builtin_amdgcn_mfma_f32_16x16x32_bf16(a, b, acc[t], 0, 0, 0);
            }
        }
        __syncthreads();
    }
    // C store (bf16)
#pragma unroll
    for (int t = 0; t < 4; ++t)
#pragma unroll
        for (int r = 0; r < 4; ++r) {
            int row = bm + w * 16 + q * 4 + r;
            if (row < M)
                C[(size_t)row * N + bn + t * 16 + r16] = __float2bfloat16(acc[t][r]);
        }
    // fused attention-score epilogue
    if (heads) {
        const int h = (heads == 4) ? blockIdx.x : 0;
        float asv[4], adv[4];
#pragma unroll
        for (int t = 0; t < 4; ++t) {
            int col = bn + t * 16 + r16;
            asv[t] = asrc[col]; adv[t] = adst[col];
        }
#pragma unroll
        for (int r = 0; r < 4; ++r) {
            int row = bm + w * 16 + q * 4 + r;
            float ss = 0.f, sd = 0.f;
#pragma unroll
            for (int t = 0; t < 4; ++t) { ss += acc[t][r] * asv[t]; sd += acc[t][r] * adv[t]; }
#pragma unroll
            for (int mask = 1; mask <= 8; mask <<= 1) {
                ss += __shfl_xor(ss, mask);
                sd += __shfl_xor(sd, mask);
            }
            if (r16 == 0 && row < M) {
                atomAddF(&ssrc[(size_t)row * heads + h], ss);
                atomAddF(&sdst[(size_t)row * heads + h], sd);
            }
        }
    }
}

// ---------------- CSR scan + scatter ----------------
__global__ __launch_bounds__(1024) void scan_kernel(const int* __restrict__ deg,
                                                    int* __restrict__ rowptr,
                                                    int* __restrict__ cursor, int N) {
    __shared__ int wsum[16];
    const int t = threadIdx.x;
    const int chunk = (N + 1023) / 1024;
    const int s0 = min(t * chunk, N), s1 = min(s0 + chunk, N);
    int sum = 0;
    for (int i = s0; i < s1; ++i) sum += deg[i];
    const int lane = t & 63, w = t >> 6;
    int v = sum;
#pragma unroll
    for (int o = 1; o < 64; o <<= 1) {
        int u = __shfl_up(v, o);
        if (lane >= o) v += u;
    }
    if (lane == 63) wsum[w] = v;
    __syncthreads();
    if (t < 16) {
        int xv = wsum[t];
#pragma unroll
        for (int o = 1; o < 16; o <<= 1) {
            int u = __shfl_up(xv, o);
            if (t >= o) xv += u;
        }
        wsum[t] = xv;
    }
    __syncthreads();
    int excl = v - sum + (w ? wsum[w - 1] : 0);
    int acc = excl;
    for (int i = s0; i < s1; ++i) { rowptr[i] = acc; cursor[i] = acc; acc += deg[i]; }
    if (s1 == N && s0 < N) rowptr[N] = acc;
}

__global__ __launch_bounds__(256) void scatter_kernel(const int* __restrict__ src,
                                                      const int* __restrict__ dst,
                                                      int* __restrict__ cursor,
                                                      int* __restrict__ csr_src,
                                                      int E, int Etot) {
    int e = blockIdx.x * blockDim.x + threadIdx.x;
    if (e >= Etot) return;
    int s, d;
    if (e < E) { s = src[e]; d = dst[e]; } else { s = d = e - E; }
    int pos = atomicAdd(cursor + d, 1);
    csr_src[pos] = s;
}

// ---------------- Layer 1 fused: wave = dst node, whole-row gathers -------------
__global__ __launch_bounds__(256) void fused1_kernel(const int* __restrict__ csr_src,
                                                     const int* __restrict__ rowptr,
                                                     const float* __restrict__ ssrc,
                                                     const float* __restrict__ sdst,
                                                     const __hip_bfloat16* __restrict__ h1,
                                                     const float* __restrict__ b,
                                                     const float* __restrict__ g,
                                                     const float* __restrict__ be,
                                                     const float* __restrict__ rm,
                                                     const float* __restrict__ rv,
                                                     __hip_bfloat16* __restrict__ out1,
                                                     int N) {
    __shared__ float4 sex[4][CAP];
    const int w = threadIdx.x >> 6;
    const int lane = threadIdx.x & 63;
    const int n = blockIdx.x * 4 + w;
    if (n >= N) return;
    const int row0 = rowptr[n], row1 = rowptr[n + 1];
    const float4 sd4 = *(const float4*)(sdst + (size_t)n * 4);

    float4 m4 = {-1e30f, -1e30f, -1e30f, -1e30f};
    for (int i = row0 + lane; i < row1; i += 64) {
        int s = csr_src[i];
        float4 sc = *(const float4*)(ssrc + (size_t)s * 4);
        sc.x = lk(sc.x + sd4.x); sc.y = lk(sc.y + sd4.y);
        sc.z = lk(sc.z + sd4.z); sc.w = lk(sc.w + sd4.w);
        int idx = i - row0;
        if (idx < CAP) sex[w][idx] = sc;
        m4.x = fmaxf(m4.x, sc.x); m4.y = fmaxf(m4.y, sc.y);
        m4.z = fmaxf(m4.z, sc.z); m4.w = fmaxf(m4.w, sc.w);
    }
#pragma unroll
    for (int o = 32; o; o >>= 1) {
        m4.x = fmaxf(m4.x, __shfl_xor(m4.x, o));
        m4.y = fmaxf(m4.y, __shfl_xor(m4.y, o));
        m4.z = fmaxf(m4.z, __shfl_xor(m4.z, o));
        m4.w = fmaxf(m4.w, __shfl_xor(m4.w, o));
    }

    float4 d4 = {0.f, 0.f, 0.f, 0.f};
    for (int i = row0 + lane; i < row1; i += 64) {
        int idx = i - row0;
        float4 sc;
        if (idx < CAP) sc = sex[w][idx];
        else {
            int s = csr_src[i];
            sc = *(const float4*)(ssrc + (size_t)s * 4);
            sc.x = lk(sc.x + sd4.x); sc.y = lk(sc.y + sd4.y);
            sc.z = lk(sc.z + sd4.z); sc.w = lk(sc.w + sd4.w);
        }
        float4 e4;
        e4.x = __expf(sc.x - m4.x); e4.y = __expf(sc.y - m4.y);
        e4.z = __expf(sc.z - m4.z); e4.w = __expf(sc.w - m4.w);
        if (idx < CAP) sex[w][idx] = e4;
        d4.x += e4.x; d4.y += e4.y; d4.z += e4.z; d4.w += e4.w;
    }
#pragma unroll
    for (int o = 32; o; o >>= 1) {
        d4.x += __shfl_xor(d4.x, o); d4.y += __shfl_xor(d4.y, o);
        d4.z += __shfl_xor(d4.z, o); d4.w += __shfl_xor(d4.w, o);
    }

    const int h = lane >> 4, c16 = lane & 15;
    const int ch = h * 64 + c16 * 4;
    const float denh = h == 0 ? d4.x : h == 1 ? d4.y : h == 2 ? d4.z : d4.w;
    const float rden = 1.f / (denh + 1e-16f);
    const __hip_bfloat16* hbase = h1 + ch;
    const float* exw = (const float*)&sex[w][0];

    f32x4 acc = {0.f, 0.f, 0.f, 0.f};
    const int end1 = min(row1, row0 + CAP);
    int i = row0;
    for (; i + 3 < end1; i += 4) {
        int s0 = csr_src[i], s1 = csr_src[i + 1], s2 = csr_src[i + 2], s3 = csr_src[i + 3];
        float a0 = exw[(i - row0) * 4 + h];
        float a1 = exw[(i - row0 + 1) * 4 + h];
        float a2 = exw[(i - row0 + 2) * 4 + h];
        float a3 = exw[(i - row0 + 3) * 4 + h];
        uint2 u0 = *(const uint2*)(hbase + (size_t)s0 * 256);
        uint2 u1 = *(const uint2*)(hbase + (size_t)s1 * 256);
        uint2 u2 = *(const uint2*)(hbase + (size_t)s2 * 256);
        uint2 u3 = *(const uint2*)(hbase + (size_t)s3 * 256);
        acc.x += a0 * bf_lo(u0.x); acc.y += a0 * bf_hi(u0.x);
        acc.z += a0 * bf_lo(u0.y); acc.w += a0 * bf_hi(u0.y);
        acc.x += a1 * bf_lo(u1.x); acc.y += a1 * bf_hi(u1.x);
        acc.z += a1 * bf_lo(u1.y); acc.w += a1 * bf_hi(u1.y);
        acc.x += a2 * bf_lo(u2.x); acc.y += a2 * bf_hi(u2.x);
        acc.z += a2 * bf_lo(u2.y); acc.w += a2 * bf_hi(u2.y);
        acc.x += a3 * bf_lo(u3.x); acc.y += a3 * bf_hi(u3.x);
        acc.z += a3 * bf_lo(u3.y); acc.w += a3 * bf_hi(u3.y);
    }
    for (; i < end1; ++i) {
        int s0 = csr_src[i];
        float a0 = exw[(i - row0) * 4 + h];
        uint2 u0 = *(const uint2*)(hbase + (size_t)s0 * 256);
        acc.x += a0 * bf_lo(u0.x); acc.y += a0 * bf_hi(u0.x);
        acc.z += a0 * bf_lo(u0.y); acc.w += a0 * bf_hi(u0.y);
    }
    if (i < row1) {   // overflow (cold)
        const float mh = h == 0 ? m4.x : h == 1 ? m4.y : h == 2 ? m4.z : m4.w;
        const float sdh = h == 0 ? sd4.x : h == 1 ? sd4.y : h == 2 ? sd4.z : sd4.w;
        for (; i < row1; ++i) {
            int s0 = csr_src[i];
            float a0 = __expf(lk(ssrc[(size_t)s0 * 4 + h] + sdh) - mh);
            uint2 u0 = *(const uint2*)(hbase + (size_t)s0 * 256);
            acc.x += a0 * bf_lo(u0.x); acc.y += a0 * bf_hi(u0.x);
            acc.z += a0 * bf_lo(u0.y); acc.w += a0 * bf_hi(u0.y);
        }
    }
    float4 bb = *(const float4*)(b + ch), gg = *(const float4*)(g + ch);
    float4 ee = *(const float4*)(be + ch), mm = *(const float4*)(rm + ch);
    float4 vv = *(const float4*)(rv + ch);
    float o0 = (acc.x * rden + bb.x - mm.x) * rsqrtf(vv.x + BN_EPS) * gg.x + ee.x;
    float o1 = (acc.y * rden + bb.y - mm.y) * rsqrtf(vv.y + BN_EPS) * gg.y + ee.y;
    float o2 = (acc.z * rden + bb.z - mm.z) * rsqrtf(vv.z + BN_EPS) * gg.z + ee.z;
    float o3 = (acc.w * rden + bb.w - mm.w) * rsqrtf(vv.w + BN_EPS) * gg.w + ee.w;
    o0 = o0 > 0.f ? o0 : expm1f(o0);
    o1 = o1 > 0.f ? o1 : expm1f(o1);
    o2 = o2 > 0.f ? o2 : expm1f(o2);
    o3 = o3 > 0.f ? o3 : expm1f(o3);
    ushort4 st;
    st.x = __bfloat16_as_ushort(__float2bfloat16(o0));
    st.y = __bfloat16_as_ushort(__float2bfloat16(o1));
    st.z = __bfloat16_as_ushort(__float2bfloat16(o2));
    st.w = __bfloat16_as_ushort(__float2bfloat16(o3));
    *(ushort4*)(out1 + (size_t)n * 256 + ch) = st;
}

// ---------------- Layer 2 fused: wave = node, 2ch/lane dword gathers -------------
__global__ __launch_bounds__(256) void fused2_kernel(const int* __restrict__ csr_src,
                                                     const int* __restrict__ rowptr,
                                                     const float* __restrict__ ssrc,
                                                     const float* __restrict__ sdst,
                                                     const __hip_bfloat16* __restrict__ h2,
                                                     const float* __restrict__ b,
                                                     const float* __restrict__ g,
                                                     const float* __restrict__ be,
                                                     const float* __restrict__ rm,
                                                     const float* __restrict__ rv,
                                                     float* __restrict__ out2,
                                                     int N) {
    __shared__ float sex[4][CAP];
    const int w = threadIdx.x >> 6;
    const int lane = threadIdx.x & 63;
    const int n = blockIdx.x * 4 + w;
    if (n >= N) return;
    const int row0 = rowptr[n], row1 = rowptr[n + 1];
    const float sd = sdst[n];

    float m = -1e30f;
    for (int i = row0 + lane; i < row1; i += 64) {
        int s = csr_src[i];
        float sc = lk(ssrc[s] + sd);
        int idx = i - row0;
        if (idx < CAP) sex[w][idx] = sc;
        m = fmaxf(m, sc);
    }
#pragma unroll
    for (int o = 32; o; o >>= 1) m = fmaxf(m, __shfl_xor(m, o));

    float den = 0.f;
    for (int i = row0 + lane; i < row1; i += 64) {
        int idx = i - row0;
        float sc = (idx < CAP) ? sex[w][idx] : lk(ssrc[csr_src[i]] + sd);
        float e = __expf(sc - m);
        if (idx < CAP) sex[w][idx] = e;
        den += e;
    }
#pragma unroll
    for (int o = 32; o; o >>= 1) den += __shfl_xor(den, o);
    const float rden = 1.f / (den + 1e-16f);

    const int ch = lane * 2;
    const __hip_bfloat16* hbase = h2 + ch;
    float ax = 0.f, ay = 0.f;
    const int end1 = min(row1, row0 + CAP);
    int i = row0;
    for (; i + 3 < end1; i += 4) {
        int s0 = csr_src[i], s1 = csr_src[i + 1], s2 = csr_src[i + 2], s3 = csr_src[i + 3];
        float a0 = sex[w][i - row0], a1 = sex[w][i - row0 + 1];
        float a2 = sex[w][i - row0 + 2], a3 = sex[w][i - row0 + 3];
        unsigned u0 = *(const unsigned*)(hbase + (size_t)s0 * 128);
        unsigned u1 = *(const unsigned*)(hbase + (size_t)s1 * 128);
        unsigned u2 = *(const unsigned*)(hbase + (size_t)s2 * 128);
        unsigned u3 = *(const unsigned*)(hbase + (size_t)s3 * 128);
        ax += a0 * bf_lo(u0); ay += a0 * bf_hi(u0);
        ax += a1 * bf_lo(u1); ay += a1 * bf_hi(u1);
        ax += a2 * bf_lo(u2); ay += a2 * bf_hi(u2);
        ax += a3 * bf_lo(u3); ay += a3 * bf_hi(u3);
    }
    for (; i < end1; ++i) {
        int s0 = csr_src[i];
        float a0 = sex[w][i - row0];
        unsigned u0 = *(const unsigned*)(hbase + (size_t)s0 * 128);
        ax += a0 * bf_lo(u0); ay += a0 * bf_hi(u0);
    }
    for (; i < row1; ++i) {   // overflow (cold)
        int s0 = csr_src[i];
        float a0 = __expf(lk(ssrc[s0] + sd) - m);
        unsigned u0 = *(const unsigned*)(hbase + (size_t)s0 * 128);
        ax += a0 * bf_lo(u0); ay += a0 * bf_hi(u0);
    }
    float2 bb = *(const float2*)(b + ch), gg = *(const float2*)(g + ch);
    float2 ee = *(const float2*)(be + ch), mm = *(const float2*)(rm + ch);
    float2 vv = *(const float2*)(rv + ch);
    float2 o;
    o.x = (ax * rden + bb.x - mm.x) * rsqrtf(vv.x + BN_EPS) * gg.x + ee.x;
    o.y = (ay * rden + bb.y - mm.y) * rsqrtf(vv.y + BN_EPS) * gg.y + ee.y;
    *(float2*)(out2 + (size_t)n * 128 + ch) = o;
}

// ---------------- pooling ----------------
__global__ __launch_bounds__(128) void pool_kernel(const float* __restrict__ out2,
                                                   const int* __restrict__ batch,
                                                   float* __restrict__ pool,
                                                   int N, int npb) {
    const int j = threadIdx.x;
    int n0 = blockIdx.x * npb;
    int n1 = min(n0 + npb, N);
    if (n0 >= n1) return;
    int curg = batch[n0];
    float acc = 0.f;
    for (int n = n0; n < n1; ++n) {
        int gr = batch[n];
        if (gr != curg) {
            atomAddF(pool + (size_t)curg * 128 + j, acc);
            acc = 0.f; curg = gr;
        }
        acc += out2[(size_t)n * 128 + j];
    }
    atomAddF(pool + (size_t)curg * 128 + j, acc);
}

__device__ __forceinline__ int lowerBound(const int* __restrict__ a, int n, int v) {
    int lo = 0, hi = n;
    while (lo < hi) {
        int mid = (lo + hi) >> 1;
        if (a[mid] < v) lo = mid + 1; else hi = mid;
    }
    return lo;
}

__global__ __launch_bounds__(256) void final_kernel(const float* __restrict__ pool,
                                                    const int* __restrict__ batch,
                                                    float* __restrict__ out, int N) {
    int i = blockIdx.x * blockDim.x + threadIdx.x;  // 0..2047
    int g = i >> 7;
    int c = lowerBound(batch, N, g + 1) - lowerBound(batch, N, g);
    out[i] = pool[i] / fmaxf((float)c, 1.f);
}

extern "C" void kernel_launch(void* const* d_in, const int* in_sizes, int n_in,
                              void* d_out, int out_size, void* d_ws, size_t ws_size,
                              hipStream_t stream) {
    const float* x    = (const float*)d_in[0];
    const int* ei     = (const int*)d_in[1];
    const int* batch  = (const int*)d_in[2];
    const float* W1   = (const float*)d_in[3];
    const float* as1  = (const float*)d_in[4];
    const float* ad1  = (const float*)d_in[5];
    const float* b1   = (const float*)d_in[6];
    const float* g1   = (const float*)d_in[7];
    const float* be1  = (const float*)d_in[8];
    const float* rm1  = (const float*)d_in[9];
    const float* rv1  = (const float*)d_in[10];
    const float* W2   = (const float*)d_in[11];
    const float* as2  = (const float*)d_in[12];
    const float* ad2  = (const float*)d_in[13];
    const float* b2   = (const float*)d_in[14];
    const float* g2   = (const float*)d_in[15];
    const float* be2  = (const float*)d_in[16];
    const float* rm2  = (const float*)d_in[17];
    const float* rv2  = (const float*)d_in[18];
    float* out = (float*)d_out;

    const int N = in_sizes[0] / 128;   // 20000
    const int E = in_sizes[1] / 2;     // 640000
    const int Etot = E + N;
    const int* src = ei;
    const int* dst = ei + E;

    // workspace carve (256B-aligned)
    char* p = (char*)d_ws;
    auto alloc = [&](size_t bytes) { char* r = p; p += (bytes + 255) & ~(size_t)255; return r; };
    __hip_bfloat16* h1   = (__hip_bfloat16*)alloc((size_t)N * 256 * 2);
    __hip_bfloat16* out1 = (__hip_bfloat16*)alloc((size_t)N * 256 * 2);
    float* out2          = (float*)alloc((size_t)N * 128 * 4);
    __hip_bfloat16* xbf  = (__hip_bfloat16*)alloc((size_t)N * 128 * 2);
    __hip_bfloat16* WT1  = (__hip_bfloat16*)alloc(256 * 128 * 2);
    __hip_bfloat16* WT2  = (__hip_bfloat16*)alloc(128 * 256 * 2);
    // scores (N*10 floats) + pool (2048) + deg (N ints) — one contiguous zeroed run
    char* zbase          = alloc((size_t)N * 10 * 4 + 2048 * 4 + (size_t)N * 4);
    float* ssrc1         = (float*)zbase;                    // N*4
    float* sdst1         = ssrc1 + (size_t)N * 4;            // N*4
    float* ssrc2         = sdst1 + (size_t)N * 4;            // N
    float* sdst2         = ssrc2 + N;                        // N
    float* pool          = sdst2 + N;                        // 2048
    int*   deg           = (int*)(pool + 2048);              // N
    int*   rowptr        = (int*)alloc((size_t)(N + 1) * 4);
    int*   cursor        = (int*)alloc((size_t)N * 4);
    int*   csrs          = (int*)alloc((size_t)Etot * 4);
    __hip_bfloat16* h2   = h1;   // alias (h1 dead after fused1)

    const size_t zbytes = (size_t)N * 10 * 4 + 2048 * 4 + (size_t)N * 4;
    hipMemsetAsync(zbase, 0, zbytes, stream);

    // ---- prep (casts + transposes + degree) ----
    const int n4 = N * 128 / 4;
    const int ptot = n4 + 2 * 128 * 256 + Etot;
    prep_deg_kernel<<<(ptot + 255) / 256, 256, 0, stream>>>(x, W1, W2, dst, xbf, WT1, WT2,
                                                            deg, n4, E, Etot);
    scan_kernel<<<1, 1024, 0, stream>>>(deg, rowptr, cursor, N);
    scatter_kernel<<<(Etot + 255) / 256, 256, 0, stream>>>(src, dst, cursor, csrs, E, Etot);

    // ---- layer 1: GEMM (+fused scores) then fused softmax/agg/BN/ELU ----
    gemm_score_kernel<<<dim3(256 / 64, (N + 63) / 64), 256, 0, stream>>>(
        xbf, WT1, h1, as1, ad1, ssrc1, sdst1, N, 256, 128, 4);
    fused1_kernel<<<(N + 3) / 4, 256, 0, stream>>>(csrs, rowptr, ssrc1, sdst1, h1,
                                                   b1, g1, be1, rm1, rv1, out1, N);
    // ---- layer 2 ----
    gemm_score_kernel<<<dim3(128 / 64, (N + 63) / 64), 256, 0, stream>>>(
        out1, WT2, h2, as2, ad2, ssrc2, sdst2, N, 128, 256, 1);
    fused2_kernel<<<(N + 3) / 4, 256, 0, stream>>>(csrs, rowptr, ssrc2, sdst2, h2,
                                                   b2, g2, be2, rm2, rv2, out2, N);

    // ---- pool ----
    pool_kernel<<<(N + 39) / 40, 128, 0, stream>>>(out2, batch, pool, N, 40);
    final_kernel<<<8, 256, 0, stream>>>(pool, batch, out, N);
}

// Round 10
// 310.583 us; speedup vs baseline: 1.3344x; 1.0385x over previous
//
#include <hip/hip_runtime.h>
#include <hip/hip_bf16.h>
#include <math.h>

#define NEG_SLOPE 0.2f
#define BN_EPS 1e-5f
#define CAP 256          // per-node LDS edge cap (deg ~ Poisson(33); overflow path below)
#define SCLAMP 60.0f     // exp-arg clamp: scores analytically << 60; inf-guard only

typedef __attribute__((ext_vector_type(8))) short bf16x8;
typedef __attribute__((ext_vector_type(4))) float f32x4;

__device__ __forceinline__ void atomAddF(float* p, float v) { unsafeAtomicAdd(p, v); }
__device__ __forceinline__ float bf_lo(unsigned u) { return __uint_as_float(u << 16); }
__device__ __forceinline__ float bf_hi(unsigned u) { return __uint_as_float(u & 0xffff0000u); }
__device__ __forceinline__ float lk(float x) { return x > 0.f ? x : NEG_SLOPE * x; }
__device__ __forceinline__ float eexp(float x) { return __expf(fminf(x, SCLAMP)); }

// ------------- prep + deg: cast x, transpose W1/W2, degree histogram ------------
__global__ __launch_bounds__(256) void prep_deg_kernel(const float* __restrict__ x,
                                                       const float* __restrict__ W1,
                                                       const float* __restrict__ W2,
                                                       const int* __restrict__ dst,
                                                       __hip_bfloat16* __restrict__ xbf,
                                                       __hip_bfloat16* __restrict__ WT1,
                                                       __hip_bfloat16* __restrict__ WT2,
                                                       int* __restrict__ deg,
                                                       int n4, int E, int Etot) {
    int i = blockIdx.x * blockDim.x + threadIdx.x;
    if (i < n4) {
        float4 v = ((const float4*)x)[i];
        ushort4 st;
        st.x = __bfloat16_as_ushort(__float2bfloat16(v.x));
        st.y = __bfloat16_as_ushort(__float2bfloat16(v.y));
        st.z = __bfloat16_as_ushort(__float2bfloat16(v.z));
        st.w = __bfloat16_as_ushort(__float2bfloat16(v.w));
        *(ushort4*)(xbf + (size_t)i * 4) = st;
        return;
    }
    int j = i - n4;
    if (j < 128 * 256) {          // W1 [128,256] -> WT1 [256,128]
        int k = j >> 8, n = j & 255;
        WT1[(size_t)n * 128 + k] = __float2bfloat16(W1[j]);
        return;
    }
    j -= 128 * 256;
    if (j < 256 * 128) {          // W2 [256,128] -> WT2 [128,256]
        int k = j >> 7, n = j & 127;
        WT2[(size_t)n * 256 + k] = __float2bfloat16(W2[j]);
        return;
    }
    j -= 256 * 128;
    if (j < Etot) {
        int d = (j < E) ? dst[j] : j - E;
        atomicAdd(deg + d, 1);
    }
}

// ------ MFMA GEMM, LDS-staged: C[M,N] = A[M,K] @ BT[N,K]^T, bf16 in/out ---------
// Fused score epilogue: per-row s_src/s_dst partials atomically accumulated.
#define LDP 68   // LDS row stride in elements (136B)
__global__ __launch_bounds__(256) void gemm_score_kernel(const __hip_bfloat16* __restrict__ A,
                                                         const __hip_bfloat16* __restrict__ BT,
                                                         __hip_bfloat16* __restrict__ C,
                                                         const float* __restrict__ asrc,
                                                         const float* __restrict__ adst,
                                                         float* __restrict__ ssrc,
                                                         float* __restrict__ sdst,
                                                         int M, int N, int K, int heads) {
    __shared__ __hip_bfloat16 As[64 * LDP];
    __shared__ __hip_bfloat16 Bs[64 * LDP];
    const int tid = threadIdx.x;
    const int w = tid >> 6;
    const int lane = tid & 63;
    const int q = lane >> 4;
    const int r16 = lane & 15;
    const int bm = blockIdx.y * 64;
    const int bn = blockIdx.x * 64;
    const int lrow = tid >> 3;
    const int lseg = tid & 7;
    f32x4 acc[4] = {};

    for (int k0 = 0; k0 < K; k0 += 64) {
#pragma unroll
        for (int half = 0; half < 2; ++half) {
            int row = lrow + half * 32;
            int ga = min(bm + row, M - 1);
            *(bf16x8*)(&As[row * LDP + lseg * 8]) =
                *(const bf16x8*)(A + (size_t)ga * K + k0 + lseg * 8);
            *(bf16x8*)(&Bs[row * LDP + lseg * 8]) =
                *(const bf16x8*)(BT + (size_t)(bn + row) * K + k0 + lseg * 8);
        }
        __syncthreads();
#pragma unroll
        for (int kk = 0; kk < 64; kk += 32) {
            bf16x8 a = *(const bf16x8*)(&As[(w * 16 + r16) * LDP + kk + q * 8]);
#pragma unroll
            for (int t = 0; t < 4; ++t) {
                bf16x8 b = *(const bf16x8*)(&Bs[(t * 16 + r16) * LDP + kk + q * 8]);
                acc[t] = __builtin_amdgcn_mfma_f32_16x16x32_bf16(a, b, acc[t], 0, 0, 0);
            }
        }
        __syncthreads();
    }
#pragma unroll
    for (int t = 0; t < 4; ++t)
#pragma unroll
        for (int r = 0; r < 4; ++r) {
            int row = bm + w * 16 + q * 4 + r;
            if (row < M)
                C[(size_t)row * N + bn + t * 16 + r16] = __float2bfloat16(acc[t][r]);
        }
    if (heads) {
        const int h = (heads == 4) ? blockIdx.x : 0;
        float asv[4], adv[4];
#pragma unroll
        for (int t = 0; t < 4; ++t) {
            int col = bn + t * 16 + r16;
            asv[t] = asrc[col]; adv[t] = adst[col];
        }
#pragma unroll
        for (int r = 0; r < 4; ++r) {
            int row = bm + w * 16 + q * 4 + r;
            float ss = 0.f, sd = 0.f;
#pragma unroll
            for (int t = 0; t < 4; ++t) { ss += acc[t][r] * asv[t]; sd += acc[t][r] * adv[t]; }
#pragma unroll
            for (int mask = 1; mask <= 8; mask <<= 1) {
                ss += __shfl_xor(ss, mask);
                sd += __shfl_xor(sd, mask);
            }
            if (r16 == 0 && row < M) {
                atomAddF(&ssrc[(size_t)row * heads + h], ss);
                atomAddF(&sdst[(size_t)row * heads + h], sd);
            }
        }
    }
}

// ---------------- CSR scan + scatter ----------------
__global__ __launch_bounds__(1024) void scan_kernel(const int* __restrict__ deg,
                                                    int* __restrict__ rowptr,
                                                    int* __restrict__ cursor, int N) {
    __shared__ int wsum[16];
    const int t = threadIdx.x;
    const int chunk = (N + 1023) / 1024;
    const int s0 = min(t * chunk, N), s1 = min(s0 + chunk, N);
    int sum = 0;
    for (int i = s0; i < s1; ++i) sum += deg[i];
    const int lane = t & 63, w = t >> 6;
    int v = sum;
#pragma unroll
    for (int o = 1; o < 64; o <<= 1) {
        int u = __shfl_up(v, o);
        if (lane >= o) v += u;
    }
    if (lane == 63) wsum[w] = v;
    __syncthreads();
    if (t < 16) {
        int xv = wsum[t];
#pragma unroll
        for (int o = 1; o < 16; o <<= 1) {
            int u = __shfl_up(xv, o);
            if (t >= o) xv += u;
        }
        wsum[t] = xv;
    }
    __syncthreads();
    int excl = v - sum + (w ? wsum[w - 1] : 0);
    int acc = excl;
    for (int i = s0; i < s1; ++i) { rowptr[i] = acc; cursor[i] = acc; acc += deg[i]; }
    if (s1 == N && s0 < N) rowptr[N] = acc;
}

__global__ __launch_bounds__(256) void scatter_kernel(const int* __restrict__ src,
                                                      const int* __restrict__ dst,
                                                      int* __restrict__ cursor,
                                                      int* __restrict__ csr_src,
                                                      int E, int Etot) {
    int e = blockIdx.x * blockDim.x + threadIdx.x;
    if (e >= Etot) return;
    int s, d;
    if (e < E) { s = src[e]; d = dst[e]; } else { s = d = e - E; }
    int pos = atomicAdd(cursor + d, 1);
    csr_src[pos] = s;
}

// ---------------- Layer 1 fused (no max-pass): exp+den, then aggregate ----------
__global__ __launch_bounds__(256) void fused1_kernel(const int* __restrict__ csr_src,
                                                     const int* __restrict__ rowptr,
                                                     const float* __restrict__ ssrc,
                                                     const float* __restrict__ sdst,
                                                     const __hip_bfloat16* __restrict__ h1,
                                                     const float* __restrict__ b,
                                                     const float* __restrict__ g,
                                                     const float* __restrict__ be,
                                                     const float* __restrict__ rm,
                                                     const float* __restrict__ rv,
                                                     __hip_bfloat16* __restrict__ out1,
                                                     int N) {
    __shared__ float4 sex[4][CAP];
    const int w = threadIdx.x >> 6;
    const int lane = threadIdx.x & 63;
    const int n = blockIdx.x * 4 + w;
    if (n >= N) return;
    const int row0 = rowptr[n], row1 = rowptr[n + 1];
    const float4 sd4 = *(const float4*)(sdst + (size_t)n * 4);

    // pass A: exp(leaky(score)) -> LDS, denominator
    float4 d4 = {0.f, 0.f, 0.f, 0.f};
    for (int i = row0 + lane; i < row1; i += 64) {
        int s = csr_src[i];
        float4 sc = *(const float4*)(ssrc + (size_t)s * 4);
        float4 e4;
        e4.x = eexp(lk(sc.x + sd4.x)); e4.y = eexp(lk(sc.y + sd4.y));
        e4.z = eexp(lk(sc.z + sd4.z)); e4.w = eexp(lk(sc.w + sd4.w));
        int idx = i - row0;
        if (idx < CAP) sex[w][idx] = e4;
        d4.x += e4.x; d4.y += e4.y; d4.z += e4.z; d4.w += e4.w;
    }
#pragma unroll
    for (int o = 32; o; o >>= 1) {
        d4.x += __shfl_xor(d4.x, o); d4.y += __shfl_xor(d4.y, o);
        d4.z += __shfl_xor(d4.z, o); d4.w += __shfl_xor(d4.w, o);
    }

    // pass B: aggregate; lane covers 4 channels of head h; 8 rows in flight
    const int h = lane >> 4, c16 = lane & 15;
    const int ch = h * 64 + c16 * 4;
    const float denh = h == 0 ? d4.x : h == 1 ? d4.y : h == 2 ? d4.z : d4.w;
    const float rden = 1.f / (denh + 1e-16f);
    const __hip_bfloat16* hbase = h1 + ch;
    const float* exw = (const float*)&sex[w][0];

    f32x4 acc = {0.f, 0.f, 0.f, 0.f};
    const int end1 = min(row1, row0 + CAP);
    int i = row0;
    for (; i + 7 < end1; i += 8) {
        int s[8]; float a[8]; uint2 u[8];
#pragma unroll
        for (int k = 0; k < 8; ++k) { s[k] = csr_src[i + k]; a[k] = exw[(i - row0 + k) * 4 + h]; }
#pragma unroll
        for (int k = 0; k < 8; ++k) u[k] = *(const uint2*)(hbase + (size_t)s[k] * 256);
#pragma unroll
        for (int k = 0; k < 8; ++k) {
            acc.x += a[k] * bf_lo(u[k].x); acc.y += a[k] * bf_hi(u[k].x);
            acc.z += a[k] * bf_lo(u[k].y); acc.w += a[k] * bf_hi(u[k].y);
        }
    }
    for (; i < end1; ++i) {
        int s0 = csr_src[i];
        float a0 = exw[(i - row0) * 4 + h];
        uint2 u0 = *(const uint2*)(hbase + (size_t)s0 * 256);
        acc.x += a0 * bf_lo(u0.x); acc.y += a0 * bf_hi(u0.x);
        acc.z += a0 * bf_lo(u0.y); acc.w += a0 * bf_hi(u0.y);
    }
    if (i < row1) {   // overflow (cold): recompute alpha inline
        const float sdh = h == 0 ? sd4.x : h == 1 ? sd4.y : h == 2 ? sd4.z : sd4.w;
        for (; i < row1; ++i) {
            int s0 = csr_src[i];
            float a0 = eexp(lk(ssrc[(size_t)s0 * 4 + h] + sdh));
            uint2 u0 = *(const uint2*)(hbase + (size_t)s0 * 256);
            acc.x += a0 * bf_lo(u0.x); acc.y += a0 * bf_hi(u0.x);
            acc.z += a0 * bf_lo(u0.y); acc.w += a0 * bf_hi(u0.y);
        }
    }
    float4 bb = *(const float4*)(b + ch), gg = *(const float4*)(g + ch);
    float4 ee = *(const float4*)(be + ch), mm = *(const float4*)(rm + ch);
    float4 vv = *(const float4*)(rv + ch);
    float o0 = (acc.x * rden + bb.x - mm.x) * rsqrtf(vv.x + BN_EPS) * gg.x + ee.x;
    float o1 = (acc.y * rden + bb.y - mm.y) * rsqrtf(vv.y + BN_EPS) * gg.y + ee.y;
    float o2 = (acc.z * rden + bb.z - mm.z) * rsqrtf(vv.z + BN_EPS) * gg.z + ee.z;
    float o3 = (acc.w * rden + bb.w - mm.w) * rsqrtf(vv.w + BN_EPS) * gg.w + ee.w;
    o0 = o0 > 0.f ? o0 : expm1f(o0);
    o1 = o1 > 0.f ? o1 : expm1f(o1);
    o2 = o2 > 0.f ? o2 : expm1f(o2);
    o3 = o3 > 0.f ? o3 : expm1f(o3);
    ushort4 st;
    st.x = __bfloat16_as_ushort(__float2bfloat16(o0));
    st.y = __bfloat16_as_ushort(__float2bfloat16(o1));
    st.z = __bfloat16_as_ushort(__float2bfloat16(o2));
    st.w = __bfloat16_as_ushort(__float2bfloat16(o3));
    *(ushort4*)(out1 + (size_t)n * 256 + ch) = st;
}

// ---------------- Layer 2 fused (no max-pass): wave = node, 2ch/lane -------------
__global__ __launch_bounds__(256) void fused2_kernel(const int* __restrict__ csr_src,
                                                     const int* __restrict__ rowptr,
                                                     const float* __restrict__ ssrc,
                                                     const float* __restrict__ sdst,
                                                     const __hip_bfloat16* __restrict__ h2,
                                                     const float* __restrict__ b,
                                                     const float* __restrict__ g,
                                                     const float* __restrict__ be,
                                                     const float* __restrict__ rm,
                                                     const float* __restrict__ rv,
                                                     float* __restrict__ out2,
                                                     int N) {
    __shared__ float sex[4][CAP];
    const int w = threadIdx.x >> 6;
    const int lane = threadIdx.x & 63;
    const int n = blockIdx.x * 4 + w;
    if (n >= N) return;
    const int row0 = rowptr[n], row1 = rowptr[n + 1];
    const float sd = sdst[n];

    float den = 0.f;
    for (int i = row0 + lane; i < row1; i += 64) {
        int s = csr_src[i];
        float e = eexp(lk(ssrc[s] + sd));
        int idx = i - row0;
        if (idx < CAP) sex[w][idx] = e;
        den += e;
    }
#pragma unroll
    for (int o = 32; o; o >>= 1) den += __shfl_xor(den, o);
    const float rden = 1.f / (den + 1e-16f);

    const int ch = lane * 2;
    const __hip_bfloat16* hbase = h2 + ch;
    float ax = 0.f, ay = 0.f;
    const int end1 = min(row1, row0 + CAP);
    int i = row0;
    for (; i + 7 < end1; i += 8) {
        int s[8]; float a[8]; unsigned u[8];
#pragma unroll
        for (int k = 0; k < 8; ++k) { s[k] = csr_src[i + k]; a[k] = sex[w][i - row0 + k]; }
#pragma unroll
        for (int k = 0; k < 8; ++k) u[k] = *(const unsigned*)(hbase + (size_t)s[k] * 128);
#pragma unroll
        for (int k = 0; k < 8; ++k) { ax += a[k] * bf_lo(u[k]); ay += a[k] * bf_hi(u[k]); }
    }
    for (; i < end1; ++i) {
        int s0 = csr_src[i];
        float a0 = sex[w][i - row0];
        unsigned u0 = *(const unsigned*)(hbase + (size_t)s0 * 128);
        ax += a0 * bf_lo(u0); ay += a0 * bf_hi(u0);
    }
    for (; i < row1; ++i) {   // overflow (cold)
        int s0 = csr_src[i];
        float a0 = eexp(lk(ssrc[s0] + sd));
        unsigned u0 = *(const unsigned*)(hbase + (size_t)s0 * 128);
        ax += a0 * bf_lo(u0); ay += a0 * bf_hi(u0);
    }
    float2 bb = *(const float2*)(b + ch), gg = *(const float2*)(g + ch);
    float2 ee = *(const float2*)(be + ch), mm = *(const float2*)(rm + ch);
    float2 vv = *(const float2*)(rv + ch);
    float2 o;
    o.x = (ax * rden + bb.x - mm.x) * rsqrtf(vv.x + BN_EPS) * gg.x + ee.x;
    o.y = (ay * rden + bb.y - mm.y) * rsqrtf(vv.y + BN_EPS) * gg.y + ee.y;
    *(float2*)(out2 + (size_t)n * 128 + ch) = o;
}

// ---------------- pooling ----------------
__global__ __launch_bounds__(128) void pool_kernel(const float* __restrict__ out2,
                                                   const int* __restrict__ batch,
                                                   float* __restrict__ pool,
                                                   int N, int npb) {
    const int j = threadIdx.x;
    int n0 = blockIdx.x * npb;
    int n1 = min(n0 + npb, N);
    if (n0 >= n1) return;
    int curg = batch[n0];
    float acc = 0.f;
    for (int n = n0; n < n1; ++n) {
        int gr = batch[n];
        if (gr != curg) {
            atomAddF(pool + (size_t)curg * 128 + j, acc);
            acc = 0.f; curg = gr;
        }
        acc += out2[(size_t)n * 128 + j];
    }
    atomAddF(pool + (size_t)curg * 128 + j, acc);
}

__device__ __forceinline__ int lowerBound(const int* __restrict__ a, int n, int v) {
    int lo = 0, hi = n;
    while (lo < hi) {
        int mid = (lo + hi) >> 1;
        if (a[mid] < v) lo = mid + 1; else hi = mid;
    }
    return lo;
}

__global__ __launch_bounds__(256) void final_kernel(const float* __restrict__ pool,
                                                    const int* __restrict__ batch,
                                                    float* __restrict__ out, int N) {
    int i = blockIdx.x * blockDim.x + threadIdx.x;  // 0..2047
    int g = i >> 7;
    int c = lowerBound(batch, N, g + 1) - lowerBound(batch, N, g);
    out[i] = pool[i] / fmaxf((float)c, 1.f);
}

extern "C" void kernel_launch(void* const* d_in, const int* in_sizes, int n_in,
                              void* d_out, int out_size, void* d_ws, size_t ws_size,
                              hipStream_t stream) {
    const float* x    = (const float*)d_in[0];
    const int* ei     = (const int*)d_in[1];
    const int* batch  = (const int*)d_in[2];
    const float* W1   = (const float*)d_in[3];
    const float* as1  = (const float*)d_in[4];
    const float* ad1  = (const float*)d_in[5];
    const float* b1   = (const float*)d_in[6];
    const float* g1   = (const float*)d_in[7];
    const float* be1  = (const float*)d_in[8];
    const float* rm1  = (const float*)d_in[9];
    const float* rv1  = (const float*)d_in[10];
    const float* W2   = (const float*)d_in[11];
    const float* as2  = (const float*)d_in[12];
    const float* ad2  = (const float*)d_in[13];
    const float* b2   = (const float*)d_in[14];
    const float* g2   = (const float*)d_in[15];
    const float* be2  = (const float*)d_in[16];
    const float* rm2  = (const float*)d_in[17];
    const float* rv2  = (const float*)d_in[18];
    float* out = (float*)d_out;

    const int N = in_sizes[0] / 128;   // 20000
    const int E = in_sizes[1] / 2;     // 640000
    const int Etot = E + N;
    const int* src = ei;
    const int* dst = ei + E;

    // workspace carve (256B-aligned)
    char* p = (char*)d_ws;
    auto alloc = [&](size_t bytes) { char* r = p; p += (bytes + 255) & ~(size_t)255; return r; };
    __hip_bfloat16* h1   = (__hip_bfloat16*)alloc((size_t)N * 256 * 2);
    __hip_bfloat16* out1 = (__hip_bfloat16*)alloc((size_t)N * 256 * 2);
    float* out2          = (float*)alloc((size_t)N * 128 * 4);
    __hip_bfloat16* xbf  = (__hip_bfloat16*)alloc((size_t)N * 128 * 2);
    __hip_bfloat16* WT1  = (__hip_bfloat16*)alloc(256 * 128 * 2);
    __hip_bfloat16* WT2  = (__hip_bfloat16*)alloc(128 * 256 * 2);
    char* zbase          = alloc((size_t)N * 10 * 4 + 2048 * 4 + (size_t)N * 4);
    float* ssrc1         = (float*)zbase;                    // N*4
    float* sdst1         = ssrc1 + (size_t)N * 4;            // N*4
    float* ssrc2         = sdst1 + (size_t)N * 4;            // N
    float* sdst2         = ssrc2 + N;                        // N
    float* pool          = sdst2 + N;                        // 2048
    int*   deg           = (int*)(pool + 2048);              // N
    int*   rowptr        = (int*)alloc((size_t)(N + 1) * 4);
    int*   cursor        = (int*)alloc((size_t)N * 4);
    int*   csrs          = (int*)alloc((size_t)Etot * 4);
    __hip_bfloat16* h2   = h1;   // alias (h1 dead after fused1)

    const size_t zbytes = (size_t)N * 10 * 4 + 2048 * 4 + (size_t)N * 4;
    hipMemsetAsync(zbase, 0, zbytes, stream);

    // ---- prep (casts + transposes + degree) ----
    const int n4 = N * 128 / 4;
    const int ptot = n4 + 2 * 128 * 256 + Etot;
    prep_deg_kernel<<<(ptot + 255) / 256, 256, 0, stream>>>(x, W1, W2, dst, xbf, WT1, WT2,
                                                            deg, n4, E, Etot);
    scan_kernel<<<1, 1024, 0, stream>>>(deg, rowptr, cursor, N);
    scatter_kernel<<<(Etot + 255) / 256, 256, 0, stream>>>(src, dst, cursor, csrs, E, Etot);

    // ---- layer 1: GEMM (+fused scores) then fused softmax/agg/BN/ELU ----
    gemm_score_kernel<<<dim3(256 / 64, (N + 63) / 64), 256, 0, stream>>>(
        xbf, WT1, h1, as1, ad1, ssrc1, sdst1, N, 256, 128, 4);
    fused1_kernel<<<(N + 3) / 4, 256, 0, stream>>>(csrs, rowptr, ssrc1, sdst1, h1,
                                                   b1, g1, be1, rm1, rv1, out1, N);
    // ---- layer 2 ----
    gemm_score_kernel<<<dim3(128 / 64, (N + 63) / 64), 256, 0, stream>>>(
        out1, WT2, h2, as2, ad2, ssrc2, sdst2, N, 128, 256, 1);
    fused2_kernel<<<(N + 3) / 4, 256, 0, stream>>>(csrs, rowptr, ssrc2, sdst2, h2,
                                                   b2, g2, be2, rm2, rv2, out2, N);

    // ---- pool ----
    pool_kernel<<<(N + 19) / 20, 128, 0, stream>>>(out2, batch, pool, N, 20);
    final_kernel<<<8, 256, 0, stream>>>(pool, batch, out, N);
}